// Round 4
// baseline (415.881 us; speedup 1.0000x reference)
//
#include <hip/hip_runtime.h>
#include <hip/hip_bf16.h>
#include <math.h>

#define B_ 2048
#define D_ 512
#define V_ 100000
#define NBUF 3

// 256x256 main GEMM geometry
#define BM2 256
#define BN2 256
#define BK2 32
#define NCT2 391              // ceil(100000/256)
#define NRT2 8                // 2048/256
#define NBLK2 (NRT2 * NCT2)   // 3128 = 8 XCD * 391

// 128x128 fallback geometry
#define BM 128
#define BN 128
#define NCT1 782              // ceil(100000/128)

constexpr float S_SCALE = 64.0f;
constexpr float COS_M_ = 0.8775825618903728f;   // cos(0.5)
constexpr float SIN_M_ = 0.479425538604203f;    // sin(0.5)
constexpr float MM_    = 0.2397127693021015f;   // sin(0.5)*0.5
constexpr float THRESH = -0.8775825618903728f;  // cos(pi-0.5)
constexpr float LOG2E  = 1.4426950408889634f;
constexpr float LN2    = 0.6931471805599453f;
constexpr float S2     = 64.0f * LOG2E;         // logits in base-2 domain

typedef __attribute__((ext_vector_type(8))) short short8;
typedef __attribute__((ext_vector_type(4))) float f32x4;

__device__ __forceinline__ unsigned short f2bf(float x) {
    __hip_bfloat16 h = __float2bfloat16(x);
    unsigned short u;
    __builtin_memcpy(&u, &h, 2);
    return u;
}

__device__ __forceinline__ void load_lds16(const unsigned short* g, unsigned short* l) {
    __builtin_amdgcn_global_load_lds(
        (const __attribute__((address_space(1))) unsigned int*)g,
        (__attribute__((address_space(3))) unsigned int*)l,
        16, 0, 0);
}

// ---------------- K1: normalize embeddings -> bf16, store rnorm_e ----------------
__global__ void k_norm_e(const float* __restrict__ e, unsigned short* __restrict__ ebf,
                         float* __restrict__ rne) {
    int row = blockIdx.x * 4 + (threadIdx.x >> 6);
    int lane = threadIdx.x & 63;
    const float4* src = (const float4*)(e + (size_t)row * D_);
    float4 a = src[lane];
    float4 b = src[lane + 64];
    float ss = a.x*a.x + a.y*a.y + a.z*a.z + a.w*a.w
             + b.x*b.x + b.y*b.y + b.z*b.z + b.w*b.w;
    #pragma unroll
    for (int d = 1; d < 64; d <<= 1) ss += __shfl_xor(ss, d, 64);
    float rn = 1.0f / fmaxf(sqrtf(ss), 1e-12f);
    ushort4* dst = (ushort4*)(ebf + (size_t)row * D_);
    dst[lane]      = make_ushort4(f2bf(a.x*rn), f2bf(a.y*rn), f2bf(a.z*rn), f2bf(a.w*rn));
    dst[lane + 64] = make_ushort4(f2bf(b.x*rn), f2bf(b.y*rn), f2bf(b.z*rn), f2bf(b.w*rn));
    if (lane == 0) rne[row] = rn;
}

// ---------------- K2: weight rnorms + normalized bf16 weight ----------------
__global__ void k_norm_w(const float* __restrict__ w, float* __restrict__ rnw,
                         unsigned short* __restrict__ wbf) {
    int row = blockIdx.x * 4 + (threadIdx.x >> 6);
    int lane = threadIdx.x & 63;
    const float4* src = (const float4*)(w + (size_t)row * D_);
    float4 a = src[lane];
    float4 b = src[lane + 64];
    float ss = a.x*a.x + a.y*a.y + a.z*a.z + a.w*a.w
             + b.x*b.x + b.y*b.y + b.z*b.z + b.w*b.w;
    #pragma unroll
    for (int d = 1; d < 64; d <<= 1) ss += __shfl_xor(ss, d, 64);
    float rn = 1.0f / fmaxf(sqrtf(ss), 1e-12f);
    if (wbf) {
        ushort4* dst = (ushort4*)(wbf + (size_t)row * D_);
        dst[lane]      = make_ushort4(f2bf(a.x*rn), f2bf(a.y*rn), f2bf(a.z*rn), f2bf(a.w*rn));
        dst[lane + 64] = make_ushort4(f2bf(b.x*rn), f2bf(b.y*rn), f2bf(b.z*rn), f2bf(b.w*rn));
    }
    if (lane == 0) rnw[row] = rn;
}

// combine two online-softmax states (base-2 domain), -inf-safe
__device__ __forceinline__ void sm_combine2(float& m, float& s, float om, float os) {
    float M = fmaxf(m, om);
    float ns = ((m  == -INFINITY) ? 0.0f : s  * __builtin_amdgcn_exp2f(m  - M))
             + ((om == -INFINITY) ? 0.0f : os * __builtin_amdgcn_exp2f(om - M));
    m = M; s = ns;
}

// ---------------- K3: 256x256 8-wave phase-split GEMM + ArcFace + lse partials ----------------
// BK=32, 3 LDS bufs, 2 phases per K-tile, counted vmcnt(4), setprio around MFMA.
// Swizzle (proven round-3 algebra): phys slot = logical ^ ((row>>1)&3), applied on the
// pre-swizzled GLOBAL source (global_load_lds dest stays linear).
__global__ __launch_bounds__(512, 2) void k_gemm256(const unsigned short* __restrict__ ebf,
                                                    const unsigned short* __restrict__ wbf,
                                                    float2* __restrict__ partials) {
    // XCD-contiguous: XCD x owns wi in [x*391, (x+1)*391); rt inner -> 8 blocks share B-panel
    const int id = blockIdx.x;
    const int wi = (id & 7) * (NBLK2 / 8) + (id >> 3);
    const int ct = wi >> 3, rt = wi & 7;
    const int row0 = rt * BM2, n0 = ct * BN2;
    const int tid = threadIdx.x, lane = tid & 63, wid = tid >> 6;
    const int wm = wid >> 2, wn = wid & 3;        // 2 x 4 wave grid

    __shared__ __align__(16) unsigned short lds[NBUF][16384]; // per buf: A[0,8192) B[8192,16384) = [256][32] each
    __shared__ float redm[4][BM2], reds[4][BM2];

    f32x4 acc[8][4];
    #pragma unroll
    for (int i = 0; i < 8; ++i)
        #pragma unroll
        for (int j = 0; j < 4; ++j)
            acc[i][j] = (f32x4){0.f, 0.f, 0.f, 0.f};

    // ---- staging source coords (constant across K-tiles) ----
    // lane tid covers LDS ushorts p = j*4096 + tid*8 -> row r = j*128 + (tid>>2),
    // phys slot = tid&3, logical chunk = (tid&3) ^ ((r>>1)&3) = (tid&3) ^ ((tid>>3)&3)
    const int c_ = (tid & 3) ^ ((tid >> 3) & 3);
    const int rstage = tid >> 2;
    const unsigned short* gA0 = ebf + (size_t)(row0 + rstage) * D_ + c_ * 8;
    const unsigned short* gA1 = gA0 + (size_t)128 * D_;
    int gb0 = n0 + rstage;       if (gb0 >= V_) gb0 = V_ - 1;   // dup row, masked in epilogue
    int gb1 = n0 + 128 + rstage; if (gb1 >= V_) gb1 = V_ - 1;
    const unsigned short* gB0 = wbf + (size_t)gb0 * D_ + c_ * 8;
    const unsigned short* gB1 = wbf + (size_t)gb1 * D_ + c_ * 8;
    const int lb = wid * 512;   // wave-uniform ushort offset within each 4096-ushort load region

    auto STAGE_A = [&](int t) {
        unsigned short* Lb = &lds[t % NBUF][0];
        const int off = t * BK2;
        load_lds16(gA0 + off, Lb + lb);
        load_lds16(gA1 + off, Lb + 4096 + lb);
    };
    auto STAGE_B = [&](int t) {
        unsigned short* Lb = &lds[t % NBUF][0];
        const int off = t * BK2;
        load_lds16(gB0 + off, Lb + 8192 + lb);
        load_lds16(gB1 + off, Lb + 12288 + lb);
    };

    // ---- ds_read byte offsets (constant): phys slot = (lane>>4) ^ ((lane>>1)&3) ----
    const int sA = ((lane >> 4) ^ ((lane >> 1) & 3)) & 3;
    int aoff[8], boff[4];
    #pragma unroll
    for (int m = 0; m < 8; ++m) {
        int r = wm * 128 + m * 16 + (lane & 15);
        aoff[m] = (r * 32 + sA * 8) * 2;
    }
    #pragma unroll
    for (int n = 0; n < 4; ++n) {
        int r = wn * 64 + n * 16 + (lane & 15);
        boff[n] = (8192 + r * 32 + sA * 8) * 2;
    }

    STAGE_A(0); STAGE_B(0);
    STAGE_A(1); STAGE_B(1);

    for (int t = 0; t < 16; ++t) {
        // own t-loads (issued at t-2) done; t+1's 4 stay in flight; then block-sync.
        if (t < 15) asm volatile("s_waitcnt vmcnt(4)" ::: "memory");
        else        asm volatile("s_waitcnt vmcnt(0)" ::: "memory");
        __builtin_amdgcn_s_barrier();

        const char* Lb = (const char*)&lds[t % NBUF][0];
        short8 af[8], bfr[4];

        // ---- phase A: quadrant m0..3 x n0..3 ----
        #pragma unroll
        for (int m = 0; m < 4; ++m) af[m] = *(const short8*)(Lb + aoff[m]);
        #pragma unroll
        for (int n = 0; n < 4; ++n) bfr[n] = *(const short8*)(Lb + boff[n]);
        if (t + 2 < 16) STAGE_A(t + 2);   // buf[(t+2)%3] last read at t-1, barrier-ordered safe
        asm volatile("s_waitcnt lgkmcnt(0)" ::: "memory");
        __builtin_amdgcn_sched_barrier(0);
        __builtin_amdgcn_s_setprio(1);
        #pragma unroll
        for (int m = 0; m < 4; ++m)
            #pragma unroll
            for (int n = 0; n < 4; ++n)
                acc[m][n] = __builtin_amdgcn_mfma_f32_16x16x32_bf16(af[m], bfr[n], acc[m][n], 0, 0, 0);
        __builtin_amdgcn_s_setprio(0);
        __builtin_amdgcn_s_barrier();

        // ---- phase B: quadrant m4..7 x n0..3 (B frags reused in-register) ----
        #pragma unroll
        for (int m = 4; m < 8; ++m) af[m] = *(const short8*)(Lb + aoff[m]);
        if (t + 2 < 16) STAGE_B(t + 2);
        asm volatile("s_waitcnt lgkmcnt(0)" ::: "memory");
        __builtin_amdgcn_sched_barrier(0);
        __builtin_amdgcn_s_setprio(1);
        #pragma unroll
        for (int m = 4; m < 8; ++m)
            #pragma unroll
            for (int n = 0; n < 4; ++n)
                acc[m][n] = __builtin_amdgcn_mfma_f32_16x16x32_bf16(af[m], bfr[n], acc[m][n], 0, 0, 0);
        __builtin_amdgcn_s_setprio(0);
        // loop-top vmcnt+barrier closes the tile
    }

    // ---- epilogue: ArcFace transform + per-row (max, sum exp2) over tile cols ----
    const int vlim = V_ - n0;
    #pragma unroll
    for (int m = 0; m < 8; ++m) {
        #pragma unroll
        for (int r = 0; r < 4; ++r) {
            float lg[4];
            float vmax = -INFINITY;
            #pragma unroll
            for (int n = 0; n < 4; ++n) {
                float c = acc[m][n][r];
                int coltile = wn * 64 + n * 16 + (lane & 15);
                c = fminf(fmaxf(c, -1.0f), 1.0f);
                float tt = fmaxf(fmaf(-c, c, 1.0f), 0.0f);
                float st = __builtin_amdgcn_sqrtf(tt);
                float cm = fmaf(c, COS_M_, -st * SIN_M_);
                cm = (c > THRESH) ? cm : (c - MM_);
                float l = cm * S2;
                lg[n] = (coltile < vlim) ? l : -INFINITY;
                vmax = fmaxf(vmax, lg[n]);
            }
            #pragma unroll
            for (int d = 1; d < 16; d <<= 1) vmax = fmaxf(vmax, __shfl_xor(vmax, d, 64));
            float vsum = 0.0f;
            #pragma unroll
            for (int n = 0; n < 4; ++n) vsum += __builtin_amdgcn_exp2f(lg[n] - vmax);
            #pragma unroll
            for (int d = 1; d < 16; d <<= 1) vsum += __shfl_xor(vsum, d, 64);
            if ((lane & 15) == 0) {
                int rowloc = wm * 128 + m * 16 + (lane >> 4) * 4 + r;
                redm[wn][rowloc] = vmax;
                reds[wn][rowloc] = vsum;   // NaN only if that 64-col strip fully invalid; discarded below
            }
        }
    }
    __syncthreads();
    if (tid < BM2) {
        float m = redm[0][tid], s = reds[0][tid];
        sm_combine2(m, s, redm[1][tid], reds[1][tid]);
        sm_combine2(m, s, redm[2][tid], reds[2][tid]);
        sm_combine2(m, s, redm[3][tid], reds[3][tid]);
        partials[(size_t)(row0 + tid) * NCT2 + ct] = make_float2(m, s);
    }
}

// ---------------- fallback GEMM (no wbf workspace): round-2 proven 128^2 path ----------------
__device__ __forceinline__ int swz64(int row, int col) {   // [128][64] ushort tile
    return (row * 64 + col) ^ ((row & 7) << 3);
}
__global__ __launch_bounds__(256) void k_gemm_fb(const unsigned short* __restrict__ ebf,
                                                 const float* __restrict__ w,
                                                 const float* __restrict__ rnw,
                                                 float2* __restrict__ partials) {
    const int rt = blockIdx.x, ct = blockIdx.y;
    const int row0 = rt * BM, n0 = ct * BN;
    const int tid = threadIdx.x, lane = tid & 63, wid = tid >> 6;
    const int wm = wid >> 1, wn = wid & 1;
    __shared__ __align__(16) unsigned short As[BM * 64];
    __shared__ __align__(16) unsigned short Bs[BN * 64];
    __shared__ float redm[2][BM], reds[2][BM];
    f32x4 acc[4][4];
    #pragma unroll
    for (int i = 0; i < 4; ++i)
        #pragma unroll
        for (int j = 0; j < 4; ++j) acc[i][j] = (f32x4){0.f, 0.f, 0.f, 0.f};
    for (int ks = 0; ks < D_ / 64; ++ks) {
        const int kk = ks * 64;
        #pragma unroll
        for (int p = 0; p < 4; ++p) {
            int idx = p * 256 + tid;
            int r = idx >> 3, c = (idx & 7) * 8;
            *(uint4*)(As + swz64(r, c)) = *(const uint4*)(ebf + (size_t)(row0 + r) * D_ + kk + c);
        }
        #pragma unroll
        for (int p = 0; p < 4; ++p) {
            int idx = p * 256 + tid;
            int r = idx >> 3, c = (idx & 7) * 8;
            int gr = n0 + r;
            uint4 val = make_uint4(0, 0, 0, 0);
            if (gr < V_) {
                float rn = rnw[gr];
                const float4* src = (const float4*)(w + (size_t)gr * D_ + kk + c);
                float4 f0 = src[0], f1 = src[1];
                val.x = (unsigned)f2bf(f0.x*rn) | ((unsigned)f2bf(f0.y*rn) << 16);
                val.y = (unsigned)f2bf(f0.z*rn) | ((unsigned)f2bf(f0.w*rn) << 16);
                val.z = (unsigned)f2bf(f1.x*rn) | ((unsigned)f2bf(f1.y*rn) << 16);
                val.w = (unsigned)f2bf(f1.z*rn) | ((unsigned)f2bf(f1.w*rn) << 16);
            }
            *(uint4*)(Bs + swz64(r, c)) = val;
        }
        __syncthreads();
        #pragma unroll
        for (int kc = 0; kc < 2; ++kc) {
            const int kbase = kc * 32 + (lane >> 4) * 8;
            short8 af[4], bfr[4];
            #pragma unroll
            for (int mf = 0; mf < 4; ++mf) af[mf] = *(const short8*)(As + swz64(wm * 64 + mf * 16 + (lane & 15), kbase));
            #pragma unroll
            for (int nf = 0; nf < 4; ++nf) bfr[nf] = *(const short8*)(Bs + swz64(wn * 64 + nf * 16 + (lane & 15), kbase));
            #pragma unroll
            for (int mf = 0; mf < 4; ++mf)
                #pragma unroll
                for (int nf = 0; nf < 4; ++nf)
                    acc[mf][nf] = __builtin_amdgcn_mfma_f32_16x16x32_bf16(af[mf], bfr[nf], acc[mf][nf], 0, 0, 0);
        }
        __syncthreads();
    }
    const int vlim = V_ - n0;
    #pragma unroll
    for (int mf = 0; mf < 4; ++mf) {
        #pragma unroll
        for (int r = 0; r < 4; ++r) {
            float lg[4];
            float vmax = -INFINITY;
            #pragma unroll
            for (int nf = 0; nf < 4; ++nf) {
                float c = acc[mf][nf][r];
                int coltile = wn * 64 + nf * 16 + (lane & 15);
                c = fminf(fmaxf(c, -1.0f), 1.0f);
                float tt = fmaxf(fmaf(-c, c, 1.0f), 0.0f);
                float st = __builtin_amdgcn_sqrtf(tt);
                float cm = fmaf(c, COS_M_, -st * SIN_M_);
                cm = (c > THRESH) ? cm : (c - MM_);
                float l = cm * S2;
                lg[nf] = (coltile < vlim) ? l : -INFINITY;
                vmax = fmaxf(vmax, lg[nf]);
            }
            #pragma unroll
            for (int d = 1; d < 16; d <<= 1) vmax = fmaxf(vmax, __shfl_xor(vmax, d, 64));
            float vsum = 0.0f;
            #pragma unroll
            for (int nf = 0; nf < 4; ++nf) vsum += __builtin_amdgcn_exp2f(lg[nf] - vmax);
            #pragma unroll
            for (int d = 1; d < 16; d <<= 1) vsum += __shfl_xor(vsum, d, 64);
            if ((lane & 15) == 0) {
                int rowloc = wm * 64 + mf * 16 + (lane >> 4) * 4 + r;
                redm[wn][rowloc] = vmax;
                reds[wn][rowloc] = vsum;
            }
        }
    }
    __syncthreads();
    if (tid < BM) {
        float m = redm[0][tid], s = reds[0][tid];
        sm_combine2(m, s, redm[1][tid], reds[1][tid]);
        partials[(size_t)(row0 + tid) * NCT1 + ct] = make_float2(m, s);
    }
}

// label dtype robustness: harness may hand int32 or int64 (LE).
__device__ __forceinline__ int get_label(const int* lab32, int b) {
    bool is64 = true;
    #pragma unroll
    for (int i = 1; i < 16; i += 2) is64 = is64 && (lab32[i] == 0);
    return is64 ? (int)(((const long long*)lab32)[b]) : lab32[b];
}

// ---------------- K4: per-row lse combine + exact f32 label logit -> nll ----------------
__global__ void k_row(const float* __restrict__ e, const float* __restrict__ w,
                      const int* __restrict__ labels, const float* __restrict__ rne,
                      const float* __restrict__ rnw, const float2* __restrict__ partials,
                      float* __restrict__ row_nll, int nct) {
    const int b = blockIdx.x;
    const int tid = threadIdx.x;

    float m = -INFINITY, s = 0.0f;
    for (int ctn = tid; ctn < nct; ctn += 256) {
        float2 p = partials[(size_t)b * nct + ctn];
        sm_combine2(m, s, p.x, p.y);
    }
    #pragma unroll
    for (int d = 1; d < 64; d <<= 1) {
        float om = __shfl_xor(m, d, 64);
        float os = __shfl_xor(s, d, 64);
        sm_combine2(m, s, om, os);
    }
    __shared__ float sm_[4], ss_[4], sd_[4];
    if ((tid & 63) == 0) { sm_[tid >> 6] = m; ss_[tid >> 6] = s; }

    int lab = get_label(labels, b);
    const float* ep = e + (size_t)b * D_;
    const float* wp = w + (size_t)lab * D_;
    float dot = ep[tid] * wp[tid] + ep[tid + 256] * wp[tid + 256];
    #pragma unroll
    for (int d = 1; d < 64; d <<= 1) dot += __shfl_xor(dot, d, 64);
    if ((tid & 63) == 0) sd_[tid >> 6] = dot;
    __syncthreads();

    if (tid == 0) {
        float M = sm_[0], S = ss_[0];
        sm_combine2(M, S, sm_[1], ss_[1]);
        sm_combine2(M, S, sm_[2], ss_[2]);
        sm_combine2(M, S, sm_[3], ss_[3]);
        float lse = (M + __builtin_amdgcn_logf(S)) * LN2;   // v_log_f32 = log2
        float c = (sd_[0] + sd_[1] + sd_[2] + sd_[3]) * rne[b] * rnw[lab];
        c = fminf(fmaxf(c, -1.0f), 1.0f);
        float st = sqrtf(fmaxf(1.0f - c * c, 0.0f));
        float cm = c * COS_M_ - st * SIN_M_;
        cm = (c > THRESH) ? cm : (c - MM_);
        row_nll[b] = lse - cm * S_SCALE;
    }
}

// ---------------- K5: mean ----------------
__global__ void k_mean(const float* __restrict__ row_nll, float* __restrict__ out) {
    int tid = threadIdx.x;
    float s = 0.0f;
    for (int i = tid; i < B_; i += 256) s += row_nll[i];
    #pragma unroll
    for (int d = 1; d < 64; d <<= 1) s += __shfl_xor(s, d, 64);
    __shared__ float sb[4];
    if ((tid & 63) == 0) sb[tid >> 6] = s;
    __syncthreads();
    if (tid == 0) out[0] = (sb[0] + sb[1] + sb[2] + sb[3]) / (float)B_;
}

extern "C" void kernel_launch(void* const* d_in, const int* in_sizes, int n_in,
                              void* d_out, int out_size, void* d_ws, size_t ws_size,
                              hipStream_t stream) {
    const float* e      = (const float*)d_in[0];
    const int*   labels = (const int*)d_in[1];
    const float* w      = (const float*)d_in[2];
    float* out = (float*)d_out;
    char* ws = (char*)d_ws;

    unsigned short* ebf = (unsigned short*)ws;                   // 2,097,152 B
    float* rne          = (float*)(ws + 2097152);                // 8,192 B
    float* rnw          = (float*)(ws + 2105344);                // 400,000 B
    float2* partials    = (float2*)(ws + 2505344);               // 12,812,288 B (sized for NCT1)
    float* row_nll      = (float*)(ws + 15317632);               // 8,192 B
    unsigned short* wbf = (unsigned short*)(ws + 15325824);      // 102,400,000 B
    const size_t NEED_PRE = 15325824 + (size_t)V_ * D_ * 2;

    const bool pre = ws_size >= NEED_PRE;

    k_norm_e<<<B_ / 4, 256, 0, stream>>>(e, ebf, rne);
    k_norm_w<<<V_ / 4, 256, 0, stream>>>(w, rnw, pre ? wbf : nullptr);
    if (pre) {
        k_gemm256<<<NBLK2, 512, 0, stream>>>(ebf, wbf, partials);
        k_row<<<B_, 256, 0, stream>>>(e, w, labels, rne, rnw, partials, row_nll, NCT2);
    } else {
        dim3 g3(B_ / BM, NCT1);
        k_gemm_fb<<<g3, 256, 0, stream>>>(ebf, w, rnw, partials);
        k_row<<<B_, 256, 0, stream>>>(e, w, labels, rne, rnw, partials, row_nll, NCT1);
    }
    k_mean<<<1, 256, 0, stream>>>(row_nll, out);
}

// Round 5
// 307.829 us; speedup vs baseline: 1.3510x; 1.3510x over previous
//
#include <hip/hip_runtime.h>
#include <hip/hip_bf16.h>
#include <math.h>

#define B_ 2048
#define D_ 512
#define V_ 100000
#define BM 128
#define BN 128
#define NCT 782           // ceil(100000/128)
#define NBLK (16 * NCT)   // 12512
#define NBUF 3
#define RED_STRIDE 20     // floats; (16*g + c) % 32 -> exact 2-way bank aliasing = free

constexpr float S_SCALE = 64.0f;
constexpr float COS_M_ = 0.8775825618903728f;   // cos(0.5)
constexpr float SIN_M_ = 0.479425538604203f;    // sin(0.5)
constexpr float MM_    = 0.2397127693021015f;   // sin(0.5)*0.5
constexpr float THRESH = -0.8775825618903728f;  // cos(pi-0.5)
constexpr float LOG2E  = 1.4426950408889634f;
constexpr float LN2    = 0.6931471805599453f;
constexpr float S2     = 64.0f * LOG2E;         // logits in base-2 domain
// Fixed-shift softmax: logits lg = cm*S2 <= S2 (92.33). Sum exp2(lg) UNSHIFTED:
// max possible sum ~ 1e5*2^92.3 = 2^109 < f32 max (2^128); for this input
// (row max lg ~ -27) sum ~ 2^-17, terms >= 2^-45 -- all in normal f32 range.

typedef __attribute__((ext_vector_type(8))) short short8;
typedef __attribute__((ext_vector_type(4))) float f32x4;

__device__ __forceinline__ unsigned short f2bf(float x) {
    __hip_bfloat16 h = __float2bfloat16(x);
    unsigned short u;
    __builtin_memcpy(&u, &h, 2);
    return u;
}

__device__ __forceinline__ void load_lds16(const unsigned short* g, unsigned short* l) {
    __builtin_amdgcn_global_load_lds(
        (const __attribute__((address_space(1))) unsigned int*)g,
        (__attribute__((address_space(3))) unsigned int*)l,
        16, 0, 0);
}

// ---------------- K1: normalize embeddings -> bf16, store rnorm_e ----------------
__global__ void k_norm_e(const float* __restrict__ e, unsigned short* __restrict__ ebf,
                         float* __restrict__ rne) {
    int row = blockIdx.x * 4 + (threadIdx.x >> 6);
    int lane = threadIdx.x & 63;
    const float4* src = (const float4*)(e + (size_t)row * D_);
    float4 a = src[lane];
    float4 b = src[lane + 64];
    float ss = a.x*a.x + a.y*a.y + a.z*a.z + a.w*a.w
             + b.x*b.x + b.y*b.y + b.z*b.z + b.w*b.w;
    #pragma unroll
    for (int d = 1; d < 64; d <<= 1) ss += __shfl_xor(ss, d, 64);
    float rn = 1.0f / fmaxf(sqrtf(ss), 1e-12f);
    ushort4* dst = (ushort4*)(ebf + (size_t)row * D_);
    dst[lane]      = make_ushort4(f2bf(a.x*rn), f2bf(a.y*rn), f2bf(a.z*rn), f2bf(a.w*rn));
    dst[lane + 64] = make_ushort4(f2bf(b.x*rn), f2bf(b.y*rn), f2bf(b.z*rn), f2bf(b.w*rn));
    if (lane == 0) rne[row] = rn;
}

// ---------------- K2: weight rnorms + normalized bf16 weight ----------------
__global__ void k_norm_w(const float* __restrict__ w, float* __restrict__ rnw,
                         unsigned short* __restrict__ wbf) {
    int row = blockIdx.x * 4 + (threadIdx.x >> 6);
    int lane = threadIdx.x & 63;
    const float4* src = (const float4*)(w + (size_t)row * D_);
    float4 a = src[lane];
    float4 b = src[lane + 64];
    float ss = a.x*a.x + a.y*a.y + a.z*a.z + a.w*a.w
             + b.x*b.x + b.y*b.y + b.z*b.z + b.w*b.w;
    #pragma unroll
    for (int d = 1; d < 64; d <<= 1) ss += __shfl_xor(ss, d, 64);
    float rn = 1.0f / fmaxf(sqrtf(ss), 1e-12f);
    if (wbf) {
        ushort4* dst = (ushort4*)(wbf + (size_t)row * D_);
        dst[lane]      = make_ushort4(f2bf(a.x*rn), f2bf(a.y*rn), f2bf(a.z*rn), f2bf(a.w*rn));
        dst[lane + 64] = make_ushort4(f2bf(b.x*rn), f2bf(b.y*rn), f2bf(b.z*rn), f2bf(b.w*rn));
    }
    if (lane == 0) rnw[row] = rn;
}

// ---------------- K3: fused GEMM + ArcFace + per-tile sum-exp2 (fixed shift) ----------------
// K-loop identical to round-3 proven version: BK=32, 3 LDS bufs, 1 s_barrier/step,
// counted vmcnt(4), source-side XOR swizzle, linear global_load_lds dest.
// Epilogue: NO cross-lane reduce -- per-lane exp2 sums into bank-padded LDS (reusing
// the K-loop buffers), then a 128-thread add pass; partials are plain f32 sums.
__global__ __launch_bounds__(256, 3) void k_gemm3(const unsigned short* __restrict__ ebf,
                                                  const unsigned short* __restrict__ wbf,
                                                  float* __restrict__ partials) {
    // XCD-contiguous work mapping: XCD x owns wi in [x*1564, (x+1)*1564)
    const int id = blockIdx.x;
    const int wi = (id & 7) * (NBLK / 8) + (id >> 3);
    const int ct = wi >> 4, rt = wi & 15;
    const int row0 = rt * BM, n0 = ct * BN;
    const int tid = threadIdx.x, lane = tid & 63, wid = tid >> 6;
    const int wm = wid >> 1, wn = wid & 1;

    __shared__ __align__(16) unsigned short lds[NBUF][8192]; // per buf: A[0..4096) B[4096..8192), [128][32] each
    float* red = (float*)&lds[0][0];   // UNION: reused after K-loop; [2][128][RED_STRIDE] = 20480 B < 49152 B

    f32x4 acc[4][4];
    #pragma unroll
    for (int i = 0; i < 4; ++i)
        #pragma unroll
        for (int j = 0; j < 4; ++j)
            acc[i][j] = (f32x4){0.f, 0.f, 0.f, 0.f};

    // ---- staging source precompute (constant across K-steps) ----
    const int sch = ((lane & 3) ^ ((lane >> 3) & 3)) & 3;
    const int ra = wid * 16 + (lane >> 2);
    const unsigned short* gA0 = ebf + (size_t)(row0 + ra) * D_ + sch * 8;
    const unsigned short* gA1 = gA0 + (size_t)64 * D_;
    int gb0 = n0 + ra;      if (gb0 >= V_) gb0 = V_ - 1;   // dup row, masked in epilogue
    int gb1 = n0 + ra + 64; if (gb1 >= V_) gb1 = V_ - 1;
    const unsigned short* gB0 = wbf + (size_t)gb0 * D_ + sch * 8;
    const unsigned short* gB1 = wbf + (size_t)gb1 * D_ + sch * 8;
    const int ldsbase = wid * 512;   // ushort offset, wave-uniform

    auto STAGE = [&](int t) {
        unsigned short* Lb = &lds[t % NBUF][0];
        const int off = t * 32;
        load_lds16(gA0 + off, Lb + ldsbase);
        load_lds16(gA1 + off, Lb + 2048 + ldsbase);
        load_lds16(gB0 + off, Lb + 4096 + ldsbase);
        load_lds16(gB1 + off, Lb + 6144 + ldsbase);
    };

    // ---- ds_read byte offsets (constant across K-steps) ----
    const int sA = ((lane >> 4) ^ ((lane >> 1) & 3)) & 3;
    int aoff[4], boff[4];
    #pragma unroll
    for (int mf = 0; mf < 4; ++mf) {
        int r = wm * 64 + mf * 16 + (lane & 15);
        aoff[mf] = (r * 32 + sA * 8) * 2;
    }
    #pragma unroll
    for (int nf = 0; nf < 4; ++nf) {
        int r = wn * 64 + nf * 16 + (lane & 15);
        boff[nf] = (4096 + r * 32 + sA * 8) * 2;
    }

    STAGE(0);
    STAGE(1);
    for (int t = 0; t < 16; ++t) {
        // wait own t-loads (issued at t-2) done; leave t+1's 4 in flight; then block-sync.
        if (t < 15) asm volatile("s_waitcnt vmcnt(4)\n\ts_barrier" ::: "memory");
        else        asm volatile("s_waitcnt vmcnt(0)\n\ts_barrier" ::: "memory");
        if (t + 2 < 16) STAGE(t + 2);   // buf[(t+2)%3] last read at t-1, barrier-ordered safe

        const char* Lb = (const char*)&lds[t % NBUF][0];
        short8 af[4], bfr[4];
        #pragma unroll
        for (int mf = 0; mf < 4; ++mf) af[mf] = *(const short8*)(Lb + aoff[mf]);
        #pragma unroll
        for (int nf = 0; nf < 4; ++nf) bfr[nf] = *(const short8*)(Lb + boff[nf]);
        #pragma unroll
        for (int mf = 0; mf < 4; ++mf)
            #pragma unroll
            for (int nf = 0; nf < 4; ++nf)
                acc[mf][nf] = __builtin_amdgcn_mfma_f32_16x16x32_bf16(af[mf], bfr[nf], acc[mf][nf], 0, 0, 0);
    }
    __syncthreads();   // K-loop LDS reads done before epilogue overwrites the buffers

    // ---- epilogue: ArcFace transform + per-lane exp2 sums (NO cross-lane reduce) ----
    const int vlim = V_ - n0;
    #pragma unroll
    for (int mf = 0; mf < 4; ++mf) {
        #pragma unroll
        for (int r = 0; r < 4; ++r) {
            float vsum = 0.0f;
            #pragma unroll
            for (int nf = 0; nf < 4; ++nf) {
                float c = acc[mf][nf][r];
                int coltile = wn * 64 + nf * 16 + (lane & 15);
                c = fminf(fmaxf(c, -1.0f), 1.0f);
                float tt = fmaxf(fmaf(-c, c, 1.0f), 0.0f);
                float st = __builtin_amdgcn_sqrtf(tt);
                float cm = fmaf(c, COS_M_, -st * SIN_M_);
                cm = (c > THRESH) ? cm : (c - MM_);
                float lg = (coltile < vlim) ? cm * S2 : -INFINITY;
                vsum += __builtin_amdgcn_exp2f(lg);   // exp2(-inf) = 0
            }
            int rowloc = wm * 64 + mf * 16 + (lane >> 4) * 4 + r;
            red[(wn * BM + rowloc) * RED_STRIDE + (lane & 15)] = vsum;
        }
    }
    __syncthreads();
    if (tid < BM) {
        const float4* p0 = (const float4*)(red + (size_t)tid * RED_STRIDE);
        const float4* p1 = (const float4*)(red + (size_t)(BM + tid) * RED_STRIDE);
        float s = 0.0f;
        #pragma unroll
        for (int q = 0; q < 4; ++q) {
            float4 u = p0[q], v = p1[q];
            s += (u.x + u.y) + (u.z + u.w) + (v.x + v.y) + (v.z + v.w);
        }
        partials[(size_t)ct * B_ + row0 + tid] = s;   // ct-major: coalesced store
    }
}

// ---------------- fallback GEMM (no wbf workspace) ----------------
__device__ __forceinline__ int swz64(int row, int col) {   // [128][64] ushort tile
    return (row * 64 + col) ^ ((row & 7) << 3);
}
__global__ __launch_bounds__(256) void k_gemm_fb(const unsigned short* __restrict__ ebf,
                                                 const float* __restrict__ w,
                                                 const float* __restrict__ rnw,
                                                 float* __restrict__ partials) {
    const int rt = blockIdx.x, ct = blockIdx.y;
    const int row0 = rt * BM, n0 = ct * BN;
    const int tid = threadIdx.x, lane = tid & 63, wid = tid >> 6;
    const int wm = wid >> 1, wn = wid & 1;
    __shared__ __align__(16) unsigned short As[BM * 64];
    __shared__ __align__(16) unsigned short Bs[BN * 64];
    float* red = (float*)&As[0];   // UNION after K-loop: 20480 B < 32768 B
    f32x4 acc[4][4];
    #pragma unroll
    for (int i = 0; i < 4; ++i)
        #pragma unroll
        for (int j = 0; j < 4; ++j) acc[i][j] = (f32x4){0.f, 0.f, 0.f, 0.f};
    for (int ks = 0; ks < D_ / 64; ++ks) {
        const int kk = ks * 64;
        #pragma unroll
        for (int p = 0; p < 4; ++p) {
            int idx = p * 256 + tid;
            int r = idx >> 3, c = (idx & 7) * 8;
            *(uint4*)(As + swz64(r, c)) = *(const uint4*)(ebf + (size_t)(row0 + r) * D_ + kk + c);
        }
        #pragma unroll
        for (int p = 0; p < 4; ++p) {
            int idx = p * 256 + tid;
            int r = idx >> 3, c = (idx & 7) * 8;
            int gr = n0 + r;
            uint4 val = make_uint4(0, 0, 0, 0);
            if (gr < V_) {
                float rn = rnw[gr];
                const float4* src = (const float4*)(w + (size_t)gr * D_ + kk + c);
                float4 f0 = src[0], f1 = src[1];
                val.x = (unsigned)f2bf(f0.x*rn) | ((unsigned)f2bf(f0.y*rn) << 16);
                val.y = (unsigned)f2bf(f0.z*rn) | ((unsigned)f2bf(f0.w*rn) << 16);
                val.z = (unsigned)f2bf(f1.x*rn) | ((unsigned)f2bf(f1.y*rn) << 16);
                val.w = (unsigned)f2bf(f1.z*rn) | ((unsigned)f2bf(f1.w*rn) << 16);
            }
            *(uint4*)(Bs + swz64(r, c)) = val;
        }
        __syncthreads();
        #pragma unroll
        for (int kc = 0; kc < 2; ++kc) {
            const int kbase = kc * 32 + (lane >> 4) * 8;
            short8 af[4], bfr[4];
            #pragma unroll
            for (int mf = 0; mf < 4; ++mf) af[mf] = *(const short8*)(As + swz64(wm * 64 + mf * 16 + (lane & 15), kbase));
            #pragma unroll
            for (int nf = 0; nf < 4; ++nf) bfr[nf] = *(const short8*)(Bs + swz64(wn * 64 + nf * 16 + (lane & 15), kbase));
            #pragma unroll
            for (int mf = 0; mf < 4; ++mf)
                #pragma unroll
                for (int nf = 0; nf < 4; ++nf)
                    acc[mf][nf] = __builtin_amdgcn_mfma_f32_16x16x32_bf16(af[mf], bfr[nf], acc[mf][nf], 0, 0, 0);
        }
        __syncthreads();
    }
    const int vlim = V_ - n0;
    #pragma unroll
    for (int mf = 0; mf < 4; ++mf) {
        #pragma unroll
        for (int r = 0; r < 4; ++r) {
            float vsum = 0.0f;
            #pragma unroll
            for (int nf = 0; nf < 4; ++nf) {
                float c = acc[mf][nf][r];
                int coltile = wn * 64 + nf * 16 + (lane & 15);
                c = fminf(fmaxf(c, -1.0f), 1.0f);
                float tt = fmaxf(fmaf(-c, c, 1.0f), 0.0f);
                float st = __builtin_amdgcn_sqrtf(tt);
                float cm = fmaf(c, COS_M_, -st * SIN_M_);
                cm = (c > THRESH) ? cm : (c - MM_);
                float lg = (coltile < vlim) ? cm * S2 : -INFINITY;
                vsum += __builtin_amdgcn_exp2f(lg);
            }
            int rowloc = wm * 64 + mf * 16 + (lane >> 4) * 4 + r;
            red[(wn * BM + rowloc) * RED_STRIDE + (lane & 15)] = vsum;
        }
    }
    __syncthreads();
    if (tid < BM) {
        const float4* p0 = (const float4*)(red + (size_t)tid * RED_STRIDE);
        const float4* p1 = (const float4*)(red + (size_t)(BM + tid) * RED_STRIDE);
        float s = 0.0f;
        #pragma unroll
        for (int q = 0; q < 4; ++q) {
            float4 u = p0[q], v = p1[q];
            s += (u.x + u.y) + (u.z + u.w) + (v.x + v.y) + (v.z + v.w);
        }
        partials[(size_t)ct * B_ + row0 + tid] = s;
    }
}

// label dtype robustness: harness may hand int32 or int64 (LE).
__device__ __forceinline__ int get_label(const int* lab32, int b) {
    bool is64 = true;
    #pragma unroll
    for (int i = 1; i < 16; i += 2) is64 = is64 && (lab32[i] == 0);
    return is64 ? (int)(((const long long*)lab32)[b]) : lab32[b];
}

// ---------------- K4: per-row sum of partials + exact f32 label logit -> nll ----------------
__global__ void k_row(const float* __restrict__ e, const float* __restrict__ w,
                      const int* __restrict__ labels, const float* __restrict__ rne,
                      const float* __restrict__ rnw, const float* __restrict__ partials,
                      float* __restrict__ row_nll) {
    const int b = blockIdx.x;
    const int tid = threadIdx.x;

    float s = 0.0f;
    for (int ctn = tid; ctn < NCT; ctn += 256) s += partials[(size_t)ctn * B_ + b];
    #pragma unroll
    for (int d = 1; d < 64; d <<= 1) s += __shfl_xor(s, d, 64);
    __shared__ float ss_[4], sd_[4];
    if ((tid & 63) == 0) ss_[tid >> 6] = s;

    int lab = get_label(labels, b);
    const float* ep = e + (size_t)b * D_;
    const float* wp = w + (size_t)lab * D_;
    float dot = ep[tid] * wp[tid] + ep[tid + 256] * wp[tid + 256];
    #pragma unroll
    for (int d = 1; d < 64; d <<= 1) dot += __shfl_xor(dot, d, 64);
    if ((tid & 63) == 0) sd_[tid >> 6] = dot;
    __syncthreads();

    if (tid == 0) {
        float S = (ss_[0] + ss_[1]) + (ss_[2] + ss_[3]);
        float lse = __builtin_amdgcn_logf(S) * LN2;   // v_log_f32 = log2; fixed shift M0=0
        float c = (sd_[0] + sd_[1] + sd_[2] + sd_[3]) * rne[b] * rnw[lab];
        c = fminf(fmaxf(c, -1.0f), 1.0f);
        float st = sqrtf(fmaxf(1.0f - c * c, 0.0f));
        float cm = c * COS_M_ - st * SIN_M_;
        cm = (c > THRESH) ? cm : (c - MM_);
        row_nll[b] = lse - cm * S_SCALE;
    }
}

// ---------------- K5: mean ----------------
__global__ void k_mean(const float* __restrict__ row_nll, float* __restrict__ out) {
    int tid = threadIdx.x;
    float s = 0.0f;
    for (int i = tid; i < B_; i += 256) s += row_nll[i];
    #pragma unroll
    for (int d = 1; d < 64; d <<= 1) s += __shfl_xor(s, d, 64);
    __shared__ float sb[4];
    if ((tid & 63) == 0) sb[tid >> 6] = s;
    __syncthreads();
    if (tid == 0) out[0] = (sb[0] + sb[1] + sb[2] + sb[3]) / (float)B_;
}

extern "C" void kernel_launch(void* const* d_in, const int* in_sizes, int n_in,
                              void* d_out, int out_size, void* d_ws, size_t ws_size,
                              hipStream_t stream) {
    const float* e      = (const float*)d_in[0];
    const int*   labels = (const int*)d_in[1];
    const float* w      = (const float*)d_in[2];
    float* out = (float*)d_out;
    char* ws = (char*)d_ws;

    unsigned short* ebf = (unsigned short*)ws;                   // 2,097,152 B
    float* rne          = (float*)(ws + 2097152);                // 8,192 B
    float* rnw          = (float*)(ws + 2105344);                // 400,000 B
    float* partials     = (float*)(ws + 2505344);                // 6,406,144 B (NCT*B_*4)
    float* row_nll      = (float*)(ws + 15317632);               // 8,192 B
    unsigned short* wbf = (unsigned short*)(ws + 15325824);      // 102,400,000 B
    const size_t NEED_PRE = 15325824 + (size_t)V_ * D_ * 2;

    const bool pre = ws_size >= NEED_PRE;

    k_norm_e<<<B_ / 4, 256, 0, stream>>>(e, ebf, rne);
    k_norm_w<<<V_ / 4, 256, 0, stream>>>(w, rnw, pre ? wbf : nullptr);
    if (pre) {
        k_gemm3<<<NBLK, 256, 0, stream>>>(ebf, wbf, partials);
    } else {
        dim3 g3(B_ / BM, NCT);
        k_gemm_fb<<<g3, 256, 0, stream>>>(ebf, w, rnw, partials);
    }
    k_row<<<B_, 256, 0, stream>>>(e, w, labels, rne, rnw, partials, row_nll);
    k_mean<<<1, 256, 0, stream>>>(row_nll, out);
}

// Round 6
// 261.085 us; speedup vs baseline: 1.5929x; 1.1790x over previous
//
#include <hip/hip_runtime.h>
#include <hip/hip_bf16.h>
#include <math.h>

#define B_ 2048
#define D_ 512
#define V_ 100000
#define BM 128
#define BN 128
#define NCT 782           // ceil(100000/128)
#define NBLK (16 * NCT)   // 12512
#define NBUF 3
#define RED_STRIDE 20     // floats; exact 2-way bank aliasing = free

constexpr float S_SCALE = 64.0f;
constexpr float COS_M_ = 0.8775825618903728f;   // cos(0.5)
constexpr float SIN_M_ = 0.479425538604203f;    // sin(0.5)
constexpr float MM_    = 0.2397127693021015f;   // sin(0.5)*0.5
constexpr float THRESH = -0.8775825618903728f;  // cos(pi-0.5)
constexpr float LOG2E  = 1.4426950408889634f;
constexpr float LN2    = 0.6931471805599453f;
constexpr float S2     = 64.0f * LOG2E;         // logits in base-2 domain
// Fixed-shift softmax: lg <= 92.33 (base-2); unshifted sum exp2(lg) stays in
// normal f32 range for any input (max 1e5*2^92.3 = 2^109 < 2^128).

typedef __attribute__((ext_vector_type(8))) short short8;
typedef __attribute__((ext_vector_type(4))) float f32x4;

__device__ __forceinline__ unsigned short f2bf(float x) {
    __hip_bfloat16 h = __float2bfloat16(x);
    unsigned short u;
    __builtin_memcpy(&u, &h, 2);
    return u;
}

__device__ __forceinline__ void load_lds16(const void* g, void* l) {
    __builtin_amdgcn_global_load_lds(
        (const __attribute__((address_space(1))) unsigned int*)g,
        (__attribute__((address_space(3))) unsigned int*)l,
        16, 0, 0);
}

// pack 4 floats -> 4 e4m3 bytes (HW RNE/sat via v_cvt_pk_fp8_f32)
__device__ __forceinline__ unsigned int pk_fp8x4(float x, float y, float z, float w) {
    int p = __builtin_amdgcn_cvt_pk_fp8_f32(x, y, 0, false);
    p = __builtin_amdgcn_cvt_pk_fp8_f32(z, w, p, true);
    return (unsigned int)p;
}

// ---------------- K1: normalize embeddings -> bf16 (fallback) + fp8 (main), rnorm_e ----------------
__global__ void k_norm_e(const float* __restrict__ e, unsigned short* __restrict__ ebf,
                         unsigned char* __restrict__ ebf8, float* __restrict__ rne) {
    int row = blockIdx.x * 4 + (threadIdx.x >> 6);
    int lane = threadIdx.x & 63;
    const float4* src = (const float4*)(e + (size_t)row * D_);
    float4 a = src[lane];
    float4 b = src[lane + 64];
    float ss = a.x*a.x + a.y*a.y + a.z*a.z + a.w*a.w
             + b.x*b.x + b.y*b.y + b.z*b.z + b.w*b.w;
    #pragma unroll
    for (int d = 1; d < 64; d <<= 1) ss += __shfl_xor(ss, d, 64);
    float rn = 1.0f / fmaxf(sqrtf(ss), 1e-12f);
    ushort4* dst = (ushort4*)(ebf + (size_t)row * D_);
    dst[lane]      = make_ushort4(f2bf(a.x*rn), f2bf(a.y*rn), f2bf(a.z*rn), f2bf(a.w*rn));
    dst[lane + 64] = make_ushort4(f2bf(b.x*rn), f2bf(b.y*rn), f2bf(b.z*rn), f2bf(b.w*rn));
    if (ebf8) {
        unsigned int* d8 = (unsigned int*)(ebf8 + (size_t)row * D_);
        d8[lane]      = pk_fp8x4(a.x*rn, a.y*rn, a.z*rn, a.w*rn);
        d8[lane + 64] = pk_fp8x4(b.x*rn, b.y*rn, b.z*rn, b.w*rn);
    }
    if (lane == 0) rne[row] = rn;
}

// ---------------- K2: weight rnorms + normalized fp8 weight ----------------
__global__ void k_norm_w(const float* __restrict__ w, float* __restrict__ rnw,
                         unsigned char* __restrict__ wbf8) {
    int row = blockIdx.x * 4 + (threadIdx.x >> 6);
    int lane = threadIdx.x & 63;
    const float4* src = (const float4*)(w + (size_t)row * D_);
    float4 a = src[lane];
    float4 b = src[lane + 64];
    float ss = a.x*a.x + a.y*a.y + a.z*a.z + a.w*a.w
             + b.x*b.x + b.y*b.y + b.z*b.z + b.w*b.w;
    #pragma unroll
    for (int d = 1; d < 64; d <<= 1) ss += __shfl_xor(ss, d, 64);
    float rn = 1.0f / fmaxf(sqrtf(ss), 1e-12f);
    if (wbf8) {
        unsigned int* d8 = (unsigned int*)(wbf8 + (size_t)row * D_);
        d8[lane]      = pk_fp8x4(a.x*rn, a.y*rn, a.z*rn, a.w*rn);
        d8[lane + 64] = pk_fp8x4(b.x*rn, b.y*rn, b.z*rn, b.w*rn);
    }
    if (lane == 0) rnw[row] = rn;
}

// ---------------- K3 (main): fp8 GEMM + ArcFace + per-tile sum-exp2 (fixed shift) ----------------
// Round-3/5 proven pipeline: BK=32, 3 LDS bufs, 1 s_barrier/step, counted vmcnt(2),
// linear global_load_lds dest. fp8 tile [128][32] BYTES: ds_read_b64 at 32B row
// stride distributes to the 4-slot/bank b64 floor -> NO swizzle needed.
// LDS/block 24KB -> 6 blocks/CU.
__global__ __launch_bounds__(256, 3) void k_gemm8(const unsigned char* __restrict__ ebf8,
                                                  const unsigned char* __restrict__ wbf8,
                                                  float* __restrict__ partials) {
    // XCD-contiguous: XCD x owns wi in [x*1564,(x+1)*1564); 16 rt per ct share B-panel
    const int id = blockIdx.x;
    const int wi = (id & 7) * (NBLK / 8) + (id >> 3);
    const int ct = wi >> 4, rt = wi & 15;
    const int row0 = rt * BM, n0 = ct * BN;
    const int tid = threadIdx.x, lane = tid & 63, wid = tid >> 6;
    const int wm = wid >> 1, wn = wid & 1;

    __shared__ __align__(16) unsigned char lds8[NBUF][8192]; // per buf: A[0,4096) B[4096,8192), [128][32]B each
    float* red = (float*)&lds8[0][0];   // UNION after K-loop: 20480 B < 24576 B

    f32x4 acc[4][4];
    #pragma unroll
    for (int i = 0; i < 4; ++i)
        #pragma unroll
        for (int j = 0; j < 4; ++j)
            acc[i][j] = (f32x4){0.f, 0.f, 0.f, 0.f};

    // ---- staging coords (constant): thread stages 16B at LDS byte tid*16 ----
    // row = tid>>1 (= wid*32 + (lane>>1)), col16 = tid&1 -> linear [128][32] tile
    const int srow = wid * 32 + (lane >> 1);
    const int scol = (lane & 1) * 16;
    const unsigned char* gA = ebf8 + (size_t)(row0 + srow) * D_ + scol;
    int gb = n0 + srow; if (gb >= V_) gb = V_ - 1;   // dup row, masked in epilogue
    const unsigned char* gB = wbf8 + (size_t)gb * D_ + scol;
    const int lb = wid * 1024;   // wave-uniform byte offset

    auto STAGE = [&](int t) {
        unsigned char* Lb = &lds8[t % NBUF][0];
        const int off = t * 32;
        load_lds16(gA + off, Lb + lb);
        load_lds16(gB + off, Lb + 4096 + lb);
    };

    // ---- ds_read_b64 byte offsets (constant): linear, no swizzle ----
    int aoff[4], boff[4];
    #pragma unroll
    for (int mf = 0; mf < 4; ++mf)
        aoff[mf] = (wm * 64 + mf * 16 + (lane & 15)) * 32 + (lane >> 4) * 8;
    #pragma unroll
    for (int nf = 0; nf < 4; ++nf)
        boff[nf] = 4096 + (wn * 64 + nf * 16 + (lane & 15)) * 32 + (lane >> 4) * 8;

    STAGE(0);
    STAGE(1);
    for (int t = 0; t < 16; ++t) {
        // own t-loads (issued at t-2) done; t+1's 2 stay in flight; then block-sync.
        if (t < 15) asm volatile("s_waitcnt vmcnt(2)\n\ts_barrier" ::: "memory");
        else        asm volatile("s_waitcnt vmcnt(0)\n\ts_barrier" ::: "memory");
        if (t + 2 < 16) STAGE(t + 2);   // buf[(t+2)%3] last read at t-1, barrier-ordered safe

        const char* Lb = (const char*)&lds8[t % NBUF][0];
        long af[4], bfr[4];
        #pragma unroll
        for (int mf = 0; mf < 4; ++mf) af[mf] = *(const long*)(Lb + aoff[mf]);
        #pragma unroll
        for (int nf = 0; nf < 4; ++nf) bfr[nf] = *(const long*)(Lb + boff[nf]);
        #pragma unroll
        for (int mf = 0; mf < 4; ++mf)
            #pragma unroll
            for (int nf = 0; nf < 4; ++nf)
                acc[mf][nf] = __builtin_amdgcn_mfma_f32_16x16x32_fp8_fp8(af[mf], bfr[nf], acc[mf][nf], 0, 0, 0);
    }
    __syncthreads();   // K-loop LDS reads done before epilogue overwrites the buffers

    // ---- epilogue: ArcFace transform + per-lane exp2 sums (no cross-lane reduce) ----
    const int vlim = V_ - n0;
    #pragma unroll
    for (int mf = 0; mf < 4; ++mf) {
        #pragma unroll
        for (int r = 0; r < 4; ++r) {
            float vsum = 0.0f;
            #pragma unroll
            for (int nf = 0; nf < 4; ++nf) {
                float c = acc[mf][nf][r];
                int coltile = wn * 64 + nf * 16 + (lane & 15);
                c = fminf(fmaxf(c, -1.0f), 1.0f);
                float tt = fmaxf(fmaf(-c, c, 1.0f), 0.0f);
                float st = __builtin_amdgcn_sqrtf(tt);
                float cm = fmaf(c, COS_M_, -st * SIN_M_);
                cm = (c > THRESH) ? cm : (c - MM_);
                float lg = (coltile < vlim) ? cm * S2 : -INFINITY;
                vsum += __builtin_amdgcn_exp2f(lg);   // exp2(-inf) = 0
            }
            int rowloc = wm * 64 + mf * 16 + (lane >> 4) * 4 + r;
            red[(wn * BM + rowloc) * RED_STRIDE + (lane & 15)] = vsum;
        }
    }
    __syncthreads();
    if (tid < BM) {
        const float4* p0 = (const float4*)(red + (size_t)tid * RED_STRIDE);
        const float4* p1 = (const float4*)(red + (size_t)(BM + tid) * RED_STRIDE);
        float s = 0.0f;
        #pragma unroll
        for (int q = 0; q < 4; ++q) {
            float4 u = p0[q], v = p1[q];
            s += (u.x + u.y) + (u.z + u.w) + (v.x + v.y) + (v.z + v.w);
        }
        partials[(size_t)ct * B_ + row0 + tid] = s;   // ct-major: coalesced store
    }
}

// ---------------- fallback GEMM (no workspace): round-5 proven bf16 path ----------------
__device__ __forceinline__ int swz64(int row, int col) {   // [128][64] ushort tile
    return (row * 64 + col) ^ ((row & 7) << 3);
}
__global__ __launch_bounds__(256) void k_gemm_fb(const unsigned short* __restrict__ ebf,
                                                 const float* __restrict__ w,
                                                 const float* __restrict__ rnw,
                                                 float* __restrict__ partials) {
    const int rt = blockIdx.x, ct = blockIdx.y;
    const int row0 = rt * BM, n0 = ct * BN;
    const int tid = threadIdx.x, lane = tid & 63, wid = tid >> 6;
    const int wm = wid >> 1, wn = wid & 1;
    __shared__ __align__(16) unsigned short As[BM * 64];
    __shared__ __align__(16) unsigned short Bs[BN * 64];
    float* red = (float*)&As[0];
    f32x4 acc[4][4];
    #pragma unroll
    for (int i = 0; i < 4; ++i)
        #pragma unroll
        for (int j = 0; j < 4; ++j) acc[i][j] = (f32x4){0.f, 0.f, 0.f, 0.f};
    for (int ks = 0; ks < D_ / 64; ++ks) {
        const int kk = ks * 64;
        #pragma unroll
        for (int p = 0; p < 4; ++p) {
            int idx = p * 256 + tid;
            int r = idx >> 3, c = (idx & 7) * 8;
            *(uint4*)(As + swz64(r, c)) = *(const uint4*)(ebf + (size_t)(row0 + r) * D_ + kk + c);
        }
        #pragma unroll
        for (int p = 0; p < 4; ++p) {
            int idx = p * 256 + tid;
            int r = idx >> 3, c = (idx & 7) * 8;
            int gr = n0 + r;
            uint4 val = make_uint4(0, 0, 0, 0);
            if (gr < V_) {
                float rn = rnw[gr];
                const float4* src = (const float4*)(w + (size_t)gr * D_ + kk + c);
                float4 f0 = src[0], f1 = src[1];
                val.x = (unsigned)f2bf(f0.x*rn) | ((unsigned)f2bf(f0.y*rn) << 16);
                val.y = (unsigned)f2bf(f0.z*rn) | ((unsigned)f2bf(f0.w*rn) << 16);
                val.z = (unsigned)f2bf(f1.x*rn) | ((unsigned)f2bf(f1.y*rn) << 16);
                val.w = (unsigned)f2bf(f1.z*rn) | ((unsigned)f2bf(f1.w*rn) << 16);
            }
            *(uint4*)(Bs + swz64(r, c)) = val;
        }
        __syncthreads();
        #pragma unroll
        for (int kc = 0; kc < 2; ++kc) {
            const int kbase = kc * 32 + (lane >> 4) * 8;
            short8 af[4], bfr[4];
            #pragma unroll
            for (int mf = 0; mf < 4; ++mf) af[mf] = *(const short8*)(As + swz64(wm * 64 + mf * 16 + (lane & 15), kbase));
            #pragma unroll
            for (int nf = 0; nf < 4; ++nf) bfr[nf] = *(const short8*)(Bs + swz64(wn * 64 + nf * 16 + (lane & 15), kbase));
            #pragma unroll
            for (int mf = 0; mf < 4; ++mf)
                #pragma unroll
                for (int nf = 0; nf < 4; ++nf)
                    acc[mf][nf] = __builtin_amdgcn_mfma_f32_16x16x32_bf16(af[mf], bfr[nf], acc[mf][nf], 0, 0, 0);
        }
        __syncthreads();
    }
    const int vlim = V_ - n0;
    #pragma unroll
    for (int mf = 0; mf < 4; ++mf) {
        #pragma unroll
        for (int r = 0; r < 4; ++r) {
            float vsum = 0.0f;
            #pragma unroll
            for (int nf = 0; nf < 4; ++nf) {
                float c = acc[mf][nf][r];
                int coltile = wn * 64 + nf * 16 + (lane & 15);
                c = fminf(fmaxf(c, -1.0f), 1.0f);
                float tt = fmaxf(fmaf(-c, c, 1.0f), 0.0f);
                float st = __builtin_amdgcn_sqrtf(tt);
                float cm = fmaf(c, COS_M_, -st * SIN_M_);
                cm = (c > THRESH) ? cm : (c - MM_);
                float lg = (coltile < vlim) ? cm * S2 : -INFINITY;
                vsum += __builtin_amdgcn_exp2f(lg);
            }
            int rowloc = wm * 64 + mf * 16 + (lane >> 4) * 4 + r;
            red[(wn * BM + rowloc) * RED_STRIDE + (lane & 15)] = vsum;
        }
    }
    __syncthreads();
    if (tid < BM) {
        const float4* p0 = (const float4*)(red + (size_t)tid * RED_STRIDE);
        const float4* p1 = (const float4*)(red + (size_t)(BM + tid) * RED_STRIDE);
        float s = 0.0f;
        #pragma unroll
        for (int q = 0; q < 4; ++q) {
            float4 u = p0[q], v = p1[q];
            s += (u.x + u.y) + (u.z + u.w) + (v.x + v.y) + (v.z + v.w);
        }
        partials[(size_t)ct * B_ + row0 + tid] = s;
    }
}

// label dtype robustness: harness may hand int32 or int64 (LE).
__device__ __forceinline__ int get_label(const int* lab32, int b) {
    bool is64 = true;
    #pragma unroll
    for (int i = 1; i < 16; i += 2) is64 = is64 && (lab32[i] == 0);
    return is64 ? (int)(((const long long*)lab32)[b]) : lab32[b];
}

// ---------------- K4: per-row sum of partials + exact f32 label logit -> nll ----------------
__global__ void k_row(const float* __restrict__ e, const float* __restrict__ w,
                      const int* __restrict__ labels, const float* __restrict__ rne,
                      const float* __restrict__ rnw, const float* __restrict__ partials,
                      float* __restrict__ row_nll) {
    const int b = blockIdx.x;
    const int tid = threadIdx.x;

    float s = 0.0f;
    for (int ctn = tid; ctn < NCT; ctn += 256) s += partials[(size_t)ctn * B_ + b];
    #pragma unroll
    for (int d = 1; d < 64; d <<= 1) s += __shfl_xor(s, d, 64);
    __shared__ float ss_[4], sd_[4];
    if ((tid & 63) == 0) ss_[tid >> 6] = s;

    int lab = get_label(labels, b);
    const float* ep = e + (size_t)b * D_;
    const float* wp = w + (size_t)lab * D_;
    float dot = ep[tid] * wp[tid] + ep[tid + 256] * wp[tid + 256];
    #pragma unroll
    for (int d = 1; d < 64; d <<= 1) dot += __shfl_xor(dot, d, 64);
    if ((tid & 63) == 0) sd_[tid >> 6] = dot;
    __syncthreads();

    if (tid == 0) {
        float S = (ss_[0] + ss_[1]) + (ss_[2] + ss_[3]);
        float lse = __builtin_amdgcn_logf(S) * LN2;   // v_log_f32 = log2; fixed shift M0=0
        float c = (sd_[0] + sd_[1] + sd_[2] + sd_[3]) * rne[b] * rnw[lab];
        c = fminf(fmaxf(c, -1.0f), 1.0f);
        float st = sqrtf(fmaxf(1.0f - c * c, 0.0f));
        float cm = c * COS_M_ - st * SIN_M_;
        cm = (c > THRESH) ? cm : (c - MM_);
        row_nll[b] = lse - cm * S_SCALE;
    }
}

// ---------------- K5: mean ----------------
__global__ void k_mean(const float* __restrict__ row_nll, float* __restrict__ out) {
    int tid = threadIdx.x;
    float s = 0.0f;
    for (int i = tid; i < B_; i += 256) s += row_nll[i];
    #pragma unroll
    for (int d = 1; d < 64; d <<= 1) s += __shfl_xor(s, d, 64);
    __shared__ float sb[4];
    if ((tid & 63) == 0) sb[tid >> 6] = s;
    __syncthreads();
    if (tid == 0) out[0] = (sb[0] + sb[1] + sb[2] + sb[3]) / (float)B_;
}

extern "C" void kernel_launch(void* const* d_in, const int* in_sizes, int n_in,
                              void* d_out, int out_size, void* d_ws, size_t ws_size,
                              hipStream_t stream) {
    const float* e      = (const float*)d_in[0];
    const int*   labels = (const int*)d_in[1];
    const float* w      = (const float*)d_in[2];
    float* out = (float*)d_out;
    char* ws = (char*)d_ws;

    unsigned short* ebf = (unsigned short*)ws;                   // 2,097,152 B
    float* rne          = (float*)(ws + 2097152);                // 8,192 B
    float* rnw          = (float*)(ws + 2105344);                // 400,000 B
    float* partials     = (float*)(ws + 2505344);                // 6,406,144 B (NCT*B_*4)
    float* row_nll      = (float*)(ws + 8911488);                // 8,192 B
    unsigned char* ebf8 = (unsigned char*)(ws + 8919680);        // 1,048,576 B
    unsigned char* wbf8 = (unsigned char*)(ws + 9968256);        // 51,200,000 B
    const size_t NEED_PRE = 9968256 + (size_t)V_ * D_;

    const bool pre = ws_size >= NEED_PRE;

    k_norm_e<<<B_ / 4, 256, 0, stream>>>(e, ebf, pre ? ebf8 : nullptr, rne);
    k_norm_w<<<V_ / 4, 256, 0, stream>>>(w, rnw, pre ? wbf8 : nullptr);
    if (pre) {
        k_gemm8<<<NBLK, 256, 0, stream>>>(ebf8, wbf8, partials);
    } else {
        dim3 g3(B_ / BM, NCT);
        k_gemm_fb<<<g3, 256, 0, stream>>>(ebf, w, rnw, partials);
    }
    k_row<<<B_, 256, 0, stream>>>(e, w, labels, rne, rnw, partials, row_nll);
    k_mean<<<1, 256, 0, stream>>>(row_nll, out);
}

// Round 7
// 255.689 us; speedup vs baseline: 1.6265x; 1.0211x over previous
//
#include <hip/hip_runtime.h>
#include <hip/hip_bf16.h>
#include <math.h>

#define B_ 2048
#define D_ 512
#define V_ 100000
#define BM 128
#define BN 128
#define NCT 782           // ceil(100000/128)
#define NBLK (16 * NCT)   // 12512
#define NBUF 3
#define RED_STRIDE 20     // floats; exact 2-way bank aliasing = free

constexpr float S_SCALE = 64.0f;
constexpr float COS_M_ = 0.8775825618903728f;   // cos(0.5)
constexpr float SIN_M_ = 0.479425538604203f;    // sin(0.5)
constexpr float MM_    = 0.2397127693021015f;   // sin(0.5)*0.5
constexpr float THRESH = -0.8775825618903728f;  // cos(pi-0.5)
constexpr float LOG2E  = 1.4426950408889634f;
constexpr float LN2    = 0.6931471805599453f;
constexpr float S2     = 64.0f * LOG2E;         // logits in base-2 domain
// Fixed-shift softmax: lg <= 92.33 (base-2); unshifted sum exp2(lg) stays in
// normal f32 range for any input (max 1e5*2^92.3 = 2^109 < 2^128).

typedef __attribute__((ext_vector_type(8))) short short8;
typedef __attribute__((ext_vector_type(4))) float f32x4;

__device__ __forceinline__ unsigned short f2bf(float x) {
    __hip_bfloat16 h = __float2bfloat16(x);
    unsigned short u;
    __builtin_memcpy(&u, &h, 2);
    return u;
}

__device__ __forceinline__ void load_lds16(const void* g, void* l) {
    __builtin_amdgcn_global_load_lds(
        (const __attribute__((address_space(1))) unsigned int*)g,
        (__attribute__((address_space(3))) unsigned int*)l,
        16, 0, 0);
}

// pack 4 floats -> 4 e4m3 bytes (HW RNE/sat via v_cvt_pk_fp8_f32)
__device__ __forceinline__ unsigned int pk_fp8x4(float x, float y, float z, float w) {
    int p = __builtin_amdgcn_cvt_pk_fp8_f32(x, y, 0, false);
    p = __builtin_amdgcn_cvt_pk_fp8_f32(z, w, p, true);
    return (unsigned int)p;
}

// ---------------- K1: normalize embeddings -> bf16 (fallback) + fp8 (main), rnorm_e ----------------
__global__ void k_norm_e(const float* __restrict__ e, unsigned short* __restrict__ ebf,
                         unsigned char* __restrict__ ebf8, float* __restrict__ rne) {
    int row = blockIdx.x * 4 + (threadIdx.x >> 6);
    int lane = threadIdx.x & 63;
    const float4* src = (const float4*)(e + (size_t)row * D_);
    float4 a = src[lane];
    float4 b = src[lane + 64];
    float ss = a.x*a.x + a.y*a.y + a.z*a.z + a.w*a.w
             + b.x*b.x + b.y*b.y + b.z*b.z + b.w*b.w;
    #pragma unroll
    for (int d = 1; d < 64; d <<= 1) ss += __shfl_xor(ss, d, 64);
    float rn = 1.0f / fmaxf(sqrtf(ss), 1e-12f);
    ushort4* dst = (ushort4*)(ebf + (size_t)row * D_);
    dst[lane]      = make_ushort4(f2bf(a.x*rn), f2bf(a.y*rn), f2bf(a.z*rn), f2bf(a.w*rn));
    dst[lane + 64] = make_ushort4(f2bf(b.x*rn), f2bf(b.y*rn), f2bf(b.z*rn), f2bf(b.w*rn));
    if (ebf8) {
        unsigned int* d8 = (unsigned int*)(ebf8 + (size_t)row * D_);
        d8[lane]      = pk_fp8x4(a.x*rn, a.y*rn, a.z*rn, a.w*rn);
        d8[lane + 64] = pk_fp8x4(b.x*rn, b.y*rn, b.z*rn, b.w*rn);
    }
    if (lane == 0) rne[row] = rn;
}

// ---------------- K2: weight rnorms + normalized fp8 weight ----------------
__global__ void k_norm_w(const float* __restrict__ w, float* __restrict__ rnw,
                         unsigned char* __restrict__ wbf8) {
    int row = blockIdx.x * 4 + (threadIdx.x >> 6);
    int lane = threadIdx.x & 63;
    const float4* src = (const float4*)(w + (size_t)row * D_);
    float4 a = src[lane];
    float4 b = src[lane + 64];
    float ss = a.x*a.x + a.y*a.y + a.z*a.z + a.w*a.w
             + b.x*b.x + b.y*b.y + b.z*b.z + b.w*b.w;
    #pragma unroll
    for (int d = 1; d < 64; d <<= 1) ss += __shfl_xor(ss, d, 64);
    float rn = 1.0f / fmaxf(sqrtf(ss), 1e-12f);
    if (wbf8) {
        unsigned int* d8 = (unsigned int*)(wbf8 + (size_t)row * D_);
        d8[lane]      = pk_fp8x4(a.x*rn, a.y*rn, a.z*rn, a.w*rn);
        d8[lane + 64] = pk_fp8x4(b.x*rn, b.y*rn, b.z*rn, b.w*rn);
    }
    if (lane == 0) rnw[row] = rn;
}

// ---------------- K3 (main): fp8 GEMM + ArcFace + per-tile sum-exp2 (fixed shift) ----------------
// Round-5 proven pipeline: BK=32, 3 LDS bufs, 1 s_barrier/step, counted vmcnt(2),
// linear global_load_lds dest. NEW (round 7): 16B-granular XOR swizzle
// slot ^= ((r>>2)&1)<<1 -- kills the 4-way b64 bank conflict (7.7e7 cycles in r6)
// while staying compatible with 16B global_load_lds staging (source pre-swizzled).
__global__ __launch_bounds__(256, 3) void k_gemm8(const unsigned char* __restrict__ ebf8,
                                                  const unsigned char* __restrict__ wbf8,
                                                  float* __restrict__ partials) {
    // XCD-contiguous: XCD x owns wi in [x*1564,(x+1)*1564); 16 rt per ct share B-panel
    const int id = blockIdx.x;
    const int wi = (id & 7) * (NBLK / 8) + (id >> 3);
    const int ct = wi >> 4, rt = wi & 15;
    const int row0 = rt * BM, n0 = ct * BN;
    const int tid = threadIdx.x, lane = tid & 63, wid = tid >> 6;
    const int wm = wid >> 1, wn = wid & 1;

    __shared__ __align__(16) unsigned char lds8[NBUF][8192]; // per buf: A[0,4096) B[4096,8192), [128][32]B each
    float* red = (float*)&lds8[0][0];   // UNION after K-loop: 20480 B < 24576 B

    f32x4 acc[4][4];
    #pragma unroll
    for (int i = 0; i < 4; ++i)
        #pragma unroll
        for (int j = 0; j < 4; ++j)
            acc[i][j] = (f32x4){0.f, 0.f, 0.f, 0.f};

    // ---- staging coords (constant): thread stages 16B at LDS byte tid*16 ----
    // row r = tid>>1, 16B-half b = tid&1. Source 16B chunk = b ^ ((r>>2)&1)
    // (inverse of the read swizzle; (r>>2)&1 == (lane>>3)&1 since tid = wid*64+lane).
    const int srow = wid * 32 + (lane >> 1);
    const int scol = ((lane & 1) ^ ((lane >> 3) & 1)) * 16;
    const unsigned char* gA = ebf8 + (size_t)(row0 + srow) * D_ + scol;
    int gb = n0 + srow; if (gb >= V_) gb = V_ - 1;   // dup row, masked in epilogue
    const unsigned char* gB = wbf8 + (size_t)gb * D_ + scol;
    const int lb = wid * 1024;   // wave-uniform byte offset

    auto STAGE = [&](int t) {
        unsigned char* Lb = &lds8[t % NBUF][0];
        const int off = t * 32;
        load_lds16(gA + off, Lb + lb);
        load_lds16(gB + off, Lb + 4096 + lb);
    };

    // ---- ds_read_b64 byte offsets (constant): slot = (lane>>4) ^ (((r>>2)&1)<<1) ----
    // r = base + (lane&15) -> (r>>2)&1 == (lane>>2)&1 (base multiple of 16).
    // Banks: each 16-lane group covers bank-pairs {0,8,16,24} then {4,12,20,28},
    // 2 lanes each = free 2-way; wave64 = uniform 4 addrs/bank = b64 floor.
    const int slot = ((lane >> 4) ^ (((lane >> 2) & 1) << 1)) & 3;
    int aoff[4], boff[4];
    #pragma unroll
    for (int mf = 0; mf < 4; ++mf)
        aoff[mf] = (wm * 64 + mf * 16 + (lane & 15)) * 32 + slot * 8;
    #pragma unroll
    for (int nf = 0; nf < 4; ++nf)
        boff[nf] = 4096 + (wn * 64 + nf * 16 + (lane & 15)) * 32 + slot * 8;

    STAGE(0);
    STAGE(1);
    for (int t = 0; t < 16; ++t) {
        // own t-loads (issued at t-2) done; t+1's 2 stay in flight; then block-sync.
        if (t < 15) asm volatile("s_waitcnt vmcnt(2)\n\ts_barrier" ::: "memory");
        else        asm volatile("s_waitcnt vmcnt(0)\n\ts_barrier" ::: "memory");
        if (t + 2 < 16) STAGE(t + 2);   // buf[(t+2)%3] last read at t-1, barrier-ordered safe

        const char* Lb = (const char*)&lds8[t % NBUF][0];
        long af[4], bfr[4];
        #pragma unroll
        for (int mf = 0; mf < 4; ++mf) af[mf] = *(const long*)(Lb + aoff[mf]);
        #pragma unroll
        for (int nf = 0; nf < 4; ++nf) bfr[nf] = *(const long*)(Lb + boff[nf]);
        #pragma unroll
        for (int mf = 0; mf < 4; ++mf)
            #pragma unroll
            for (int nf = 0; nf < 4; ++nf)
                acc[mf][nf] = __builtin_amdgcn_mfma_f32_16x16x32_fp8_fp8(af[mf], bfr[nf], acc[mf][nf], 0, 0, 0);
    }
    __syncthreads();   // K-loop LDS reads done before epilogue overwrites the buffers

    // ---- epilogue: ArcFace transform + per-lane exp2 sums (no cross-lane reduce) ----
    const int vlim = V_ - n0;
    #pragma unroll
    for (int mf = 0; mf < 4; ++mf) {
        #pragma unroll
        for (int r = 0; r < 4; ++r) {
            float vsum = 0.0f;
            #pragma unroll
            for (int nf = 0; nf < 4; ++nf) {
                float c = acc[mf][nf][r];
                int coltile = wn * 64 + nf * 16 + (lane & 15);
                c = fminf(fmaxf(c, -1.0f), 1.0f);
                float tt = fmaxf(fmaf(-c, c, 1.0f), 0.0f);
                float st = __builtin_amdgcn_sqrtf(tt);
                float cm = fmaf(c, COS_M_, -st * SIN_M_);
                cm = (c > THRESH) ? cm : (c - MM_);
                float lg = (coltile < vlim) ? cm * S2 : -INFINITY;
                vsum += __builtin_amdgcn_exp2f(lg);   // exp2(-inf) = 0
            }
            int rowloc = wm * 64 + mf * 16 + (lane >> 4) * 4 + r;
            red[(wn * BM + rowloc) * RED_STRIDE + (lane & 15)] = vsum;
        }
    }
    __syncthreads();
    if (tid < BM) {
        const float4* p0 = (const float4*)(red + (size_t)tid * RED_STRIDE);
        const float4* p1 = (const float4*)(red + (size_t)(BM + tid) * RED_STRIDE);
        float s = 0.0f;
        #pragma unroll
        for (int q = 0; q < 4; ++q) {
            float4 u = p0[q], v = p1[q];
            s += (u.x + u.y) + (u.z + u.w) + (v.x + v.y) + (v.z + v.w);
        }
        partials[(size_t)ct * B_ + row0 + tid] = s;   // ct-major: coalesced store
    }
}

// ---------------- fallback GEMM (no workspace): round-5 proven bf16 path ----------------
__device__ __forceinline__ int swz64(int row, int col) {   // [128][64] ushort tile
    return (row * 64 + col) ^ ((row & 7) << 3);
}
__global__ __launch_bounds__(256) void k_gemm_fb(const unsigned short* __restrict__ ebf,
                                                 const float* __restrict__ w,
                                                 const float* __restrict__ rnw,
                                                 float* __restrict__ partials) {
    const int rt = blockIdx.x, ct = blockIdx.y;
    const int row0 = rt * BM, n0 = ct * BN;
    const int tid = threadIdx.x, lane = tid & 63, wid = tid >> 6;
    const int wm = wid >> 1, wn = wid & 1;
    __shared__ __align__(16) unsigned short As[BM * 64];
    __shared__ __align__(16) unsigned short Bs[BN * 64];
    float* red = (float*)&As[0];
    f32x4 acc[4][4];
    #pragma unroll
    for (int i = 0; i < 4; ++i)
        #pragma unroll
        for (int j = 0; j < 4; ++j) acc[i][j] = (f32x4){0.f, 0.f, 0.f, 0.f};
    for (int ks = 0; ks < D_ / 64; ++ks) {
        const int kk = ks * 64;
        #pragma unroll
        for (int p = 0; p < 4; ++p) {
            int idx = p * 256 + tid;
            int r = idx >> 3, c = (idx & 7) * 8;
            *(uint4*)(As + swz64(r, c)) = *(const uint4*)(ebf + (size_t)(row0 + r) * D_ + kk + c);
        }
        #pragma unroll
        for (int p = 0; p < 4; ++p) {
            int idx = p * 256 + tid;
            int r = idx >> 3, c = (idx & 7) * 8;
            int gr = n0 + r;
            uint4 val = make_uint4(0, 0, 0, 0);
            if (gr < V_) {
                float rn = rnw[gr];
                const float4* src = (const float4*)(w + (size_t)gr * D_ + kk + c);
                float4 f0 = src[0], f1 = src[1];
                val.x = (unsigned)f2bf(f0.x*rn) | ((unsigned)f2bf(f0.y*rn) << 16);
                val.y = (unsigned)f2bf(f0.z*rn) | ((unsigned)f2bf(f0.w*rn) << 16);
                val.z = (unsigned)f2bf(f1.x*rn) | ((unsigned)f2bf(f1.y*rn) << 16);
                val.w = (unsigned)f2bf(f1.z*rn) | ((unsigned)f2bf(f1.w*rn) << 16);
            }
            *(uint4*)(Bs + swz64(r, c)) = val;
        }
        __syncthreads();
        #pragma unroll
        for (int kc = 0; kc < 2; ++kc) {
            const int kbase = kc * 32 + (lane >> 4) * 8;
            short8 af[4], bfr[4];
            #pragma unroll
            for (int mf = 0; mf < 4; ++mf) af[mf] = *(const short8*)(As + swz64(wm * 64 + mf * 16 + (lane & 15), kbase));
            #pragma unroll
            for (int nf = 0; nf < 4; ++nf) bfr[nf] = *(const short8*)(Bs + swz64(wn * 64 + nf * 16 + (lane & 15), kbase));
            #pragma unroll
            for (int mf = 0; mf < 4; ++mf)
                #pragma unroll
                for (int nf = 0; nf < 4; ++nf)
                    acc[mf][nf] = __builtin_amdgcn_mfma_f32_16x16x32_bf16(af[mf], bfr[nf], acc[mf][nf], 0, 0, 0);
        }
        __syncthreads();
    }
    const int vlim = V_ - n0;
    #pragma unroll
    for (int mf = 0; mf < 4; ++mf) {
        #pragma unroll
        for (int r = 0; r < 4; ++r) {
            float vsum = 0.0f;
            #pragma unroll
            for (int nf = 0; nf < 4; ++nf) {
                float c = acc[mf][nf][r];
                int coltile = wn * 64 + nf * 16 + (lane & 15);
                c = fminf(fmaxf(c, -1.0f), 1.0f);
                float tt = fmaxf(fmaf(-c, c, 1.0f), 0.0f);
                float st = __builtin_amdgcn_sqrtf(tt);
                float cm = fmaf(c, COS_M_, -st * SIN_M_);
                cm = (c > THRESH) ? cm : (c - MM_);
                float lg = (coltile < vlim) ? cm * S2 : -INFINITY;
                vsum += __builtin_amdgcn_exp2f(lg);
            }
            int rowloc = wm * 64 + mf * 16 + (lane >> 4) * 4 + r;
            red[(wn * BM + rowloc) * RED_STRIDE + (lane & 15)] = vsum;
        }
    }
    __syncthreads();
    if (tid < BM) {
        const float4* p0 = (const float4*)(red + (size_t)tid * RED_STRIDE);
        const float4* p1 = (const float4*)(red + (size_t)(BM + tid) * RED_STRIDE);
        float s = 0.0f;
        #pragma unroll
        for (int q = 0; q < 4; ++q) {
            float4 u = p0[q], v = p1[q];
            s += (u.x + u.y) + (u.z + u.w) + (v.x + v.y) + (v.z + v.w);
        }
        partials[(size_t)ct * B_ + row0 + tid] = s;
    }
}

// label dtype robustness: harness may hand int32 or int64 (LE).
__device__ __forceinline__ int get_label(const int* lab32, int b) {
    bool is64 = true;
    #pragma unroll
    for (int i = 1; i < 16; i += 2) is64 = is64 && (lab32[i] == 0);
    return is64 ? (int)(((const long long*)lab32)[b]) : lab32[b];
}

// ---------------- K4: per-row sum of partials + exact f32 label logit -> nll ----------------
__global__ void k_row(const float* __restrict__ e, const float* __restrict__ w,
                      const int* __restrict__ labels, const float* __restrict__ rne,
                      const float* __restrict__ rnw, const float* __restrict__ partials,
                      float* __restrict__ row_nll) {
    const int b = blockIdx.x;
    const int tid = threadIdx.x;

    float s = 0.0f;
    for (int ctn = tid; ctn < NCT; ctn += 256) s += partials[(size_t)ctn * B_ + b];
    #pragma unroll
    for (int d = 1; d < 64; d <<= 1) s += __shfl_xor(s, d, 64);
    __shared__ float ss_[4], sd_[4];
    if ((tid & 63) == 0) ss_[tid >> 6] = s;

    int lab = get_label(labels, b);
    const float* ep = e + (size_t)b * D_;
    const float* wp = w + (size_t)lab * D_;
    float dot = ep[tid] * wp[tid] + ep[tid + 256] * wp[tid + 256];
    #pragma unroll
    for (int d = 1; d < 64; d <<= 1) dot += __shfl_xor(dot, d, 64);
    if ((tid & 63) == 0) sd_[tid >> 6] = dot;
    __syncthreads();

    if (tid == 0) {
        float S = (ss_[0] + ss_[1]) + (ss_[2] + ss_[3]);
        float lse = __builtin_amdgcn_logf(S) * LN2;   // v_log_f32 = log2; fixed shift M0=0
        float c = (sd_[0] + sd_[1] + sd_[2] + sd_[3]) * rne[b] * rnw[lab];
        c = fminf(fmaxf(c, -1.0f), 1.0f);
        float st = sqrtf(fmaxf(1.0f - c * c, 0.0f));
        float cm = c * COS_M_ - st * SIN_M_;
        cm = (c > THRESH) ? cm : (c - MM_);
        row_nll[b] = lse - cm * S_SCALE;
    }
}

// ---------------- K5: mean ----------------
__global__ void k_mean(const float* __restrict__ row_nll, float* __restrict__ out) {
    int tid = threadIdx.x;
    float s = 0.0f;
    for (int i = tid; i < B_; i += 256) s += row_nll[i];
    #pragma unroll
    for (int d = 1; d < 64; d <<= 1) s += __shfl_xor(s, d, 64);
    __shared__ float sb[4];
    if ((tid & 63) == 0) sb[tid >> 6] = s;
    __syncthreads();
    if (tid == 0) out[0] = (sb[0] + sb[1] + sb[2] + sb[3]) / (float)B_;
}

extern "C" void kernel_launch(void* const* d_in, const int* in_sizes, int n_in,
                              void* d_out, int out_size, void* d_ws, size_t ws_size,
                              hipStream_t stream) {
    const float* e      = (const float*)d_in[0];
    const int*   labels = (const int*)d_in[1];
    const float* w      = (const float*)d_in[2];
    float* out = (float*)d_out;
    char* ws = (char*)d_ws;

    unsigned short* ebf = (unsigned short*)ws;                   // 2,097,152 B
    float* rne          = (float*)(ws + 2097152);                // 8,192 B
    float* rnw          = (float*)(ws + 2105344);                // 400,000 B
    float* partials     = (float*)(ws + 2505344);                // 6,406,144 B (NCT*B_*4)
    float* row_nll      = (float*)(ws + 8911488);                // 8,192 B
    unsigned char* ebf8 = (unsigned char*)(ws + 8919680);        // 1,048,576 B
    unsigned char* wbf8 = (unsigned char*)(ws + 9968256);        // 51,200,000 B
    const size_t NEED_PRE = 9968256 + (size_t)V_ * D_;

    const bool pre = ws_size >= NEED_PRE;

    k_norm_e<<<B_ / 4, 256, 0, stream>>>(e, ebf, pre ? ebf8 : nullptr, rne);
    k_norm_w<<<V_ / 4, 256, 0, stream>>>(w, rnw, pre ? wbf8 : nullptr);
    if (pre) {
        k_gemm8<<<NBLK, 256, 0, stream>>>(ebf8, wbf8, partials);
    } else {
        dim3 g3(B_ / BM, NCT);
        k_gemm_fb<<<g3, 256, 0, stream>>>(ebf, w, rnw, partials);
    }
    k_row<<<B_, 256, 0, stream>>>(e, w, labels, rne, rnw, partials, row_nll);
    k_mean<<<1, 256, 0, stream>>>(row_nll, out);
}

// Round 8
// 216.905 us; speedup vs baseline: 1.9173x; 1.1788x over previous
//
#include <hip/hip_runtime.h>
#include <hip/hip_bf16.h>
#include <math.h>

#define B_ 2048
#define D_ 512
#define V_ 100000
#define BM 128
#define BN 128
#define NCT 782           // ceil(100000/128)
#define NBLK (16 * NCT)   // 12512
#define NBUF 3
#define RED_STRIDE 20     // floats; exact 2-way bank aliasing = free

constexpr float S_SCALE = 64.0f;
constexpr float COS_M_ = 0.8775825618903728f;   // cos(0.5)
constexpr float SIN_M_ = 0.479425538604203f;    // sin(0.5)
constexpr float MM_    = 0.2397127693021015f;   // sin(0.5)*0.5
constexpr float THRESH = -0.8775825618903728f;  // cos(pi-0.5)
constexpr float LOG2E  = 1.4426950408889634f;
constexpr float LN2    = 0.6931471805599453f;
constexpr float S2     = 64.0f * LOG2E;         // logits in base-2 domain
// Fixed-shift softmax: lg <= 92.33 (base-2); unshifted sum exp2(lg) stays in
// normal f32 range for any input (max 1e5*2^92.3 = 2^109 < 2^128).

typedef __attribute__((ext_vector_type(8))) short short8;
typedef __attribute__((ext_vector_type(4))) float f32x4;
typedef __attribute__((ext_vector_type(2))) long long2_t;

__device__ __forceinline__ unsigned short f2bf(float x) {
    __hip_bfloat16 h = __float2bfloat16(x);
    unsigned short u;
    __builtin_memcpy(&u, &h, 2);
    return u;
}

__device__ __forceinline__ void load_lds16(const void* g, void* l) {
    __builtin_amdgcn_global_load_lds(
        (const __attribute__((address_space(1))) unsigned int*)g,
        (__attribute__((address_space(3))) unsigned int*)l,
        16, 0, 0);
}

// pack 4 floats -> 4 e4m3 bytes (HW RNE/sat via v_cvt_pk_fp8_f32)
__device__ __forceinline__ unsigned int pk_fp8x4(float x, float y, float z, float w) {
    int p = __builtin_amdgcn_cvt_pk_fp8_f32(x, y, 0, false);
    p = __builtin_amdgcn_cvt_pk_fp8_f32(z, w, p, true);
    return (unsigned int)p;
}

// k-column permutation (4B-block granularity) applied to BOTH fp8 operands:
// within each 64-byte k-group, orig (ks,c,h) [k = 32ks+8c+4h] -> perm block 4c+2ks+h.
// Lane's two 8B MFMA frags (ks=0,1 at chunk c) become ONE contiguous 16B chunk ->
// ds_read_b128 with the round-5-proven 16B-slot XOR swizzle (0 bank conflicts).
// Correct for any bijection within the 64-group applied to both A and B.
__device__ __forceinline__ int permj(int j) {   // j = 4B-block index within row
    return (j & ~15) | (((j >> 1) & 3) << 2) | (((j >> 3) & 1) << 1) | (j & 1);
}

// ---------------- K1: normalize embeddings -> bf16 (fallback) + permuted fp8, rnorm_e ----------------
__global__ void k_norm_e(const float* __restrict__ e, unsigned short* __restrict__ ebf,
                         unsigned char* __restrict__ ebf8, float* __restrict__ rne) {
    int row = blockIdx.x * 4 + (threadIdx.x >> 6);
    int lane = threadIdx.x & 63;
    const float4* src = (const float4*)(e + (size_t)row * D_);
    float4 a = src[lane];
    float4 b = src[lane + 64];
    float ss = a.x*a.x + a.y*a.y + a.z*a.z + a.w*a.w
             + b.x*b.x + b.y*b.y + b.z*b.z + b.w*b.w;
    #pragma unroll
    for (int d = 1; d < 64; d <<= 1) ss += __shfl_xor(ss, d, 64);
    float rn = 1.0f / fmaxf(sqrtf(ss), 1e-12f);
    ushort4* dst = (ushort4*)(ebf + (size_t)row * D_);
    dst[lane]      = make_ushort4(f2bf(a.x*rn), f2bf(a.y*rn), f2bf(a.z*rn), f2bf(a.w*rn));
    dst[lane + 64] = make_ushort4(f2bf(b.x*rn), f2bf(b.y*rn), f2bf(b.z*rn), f2bf(b.w*rn));
    if (ebf8) {
        unsigned int* d8 = (unsigned int*)(ebf8 + (size_t)row * D_);
        d8[permj(lane)]      = pk_fp8x4(a.x*rn, a.y*rn, a.z*rn, a.w*rn);
        d8[permj(lane + 64)] = pk_fp8x4(b.x*rn, b.y*rn, b.z*rn, b.w*rn);
    }
    if (lane == 0) rne[row] = rn;
}

// ---------------- K2: weight rnorms + normalized permuted fp8 weight ----------------
__global__ void k_norm_w(const float* __restrict__ w, float* __restrict__ rnw,
                         unsigned char* __restrict__ wbf8) {
    int row = blockIdx.x * 4 + (threadIdx.x >> 6);
    int lane = threadIdx.x & 63;
    const float4* src = (const float4*)(w + (size_t)row * D_);
    float4 a = src[lane];
    float4 b = src[lane + 64];
    float ss = a.x*a.x + a.y*a.y + a.z*a.z + a.w*a.w
             + b.x*b.x + b.y*b.y + b.z*b.z + b.w*b.w;
    #pragma unroll
    for (int d = 1; d < 64; d <<= 1) ss += __shfl_xor(ss, d, 64);
    float rn = 1.0f / fmaxf(sqrtf(ss), 1e-12f);
    if (wbf8) {
        unsigned int* d8 = (unsigned int*)(wbf8 + (size_t)row * D_);
        d8[permj(lane)]      = pk_fp8x4(a.x*rn, a.y*rn, a.z*rn, a.w*rn);
        d8[permj(lane + 64)] = pk_fp8x4(b.x*rn, b.y*rn, b.z*rn, b.w*rn);
    }
    if (lane == 0) rnw[row] = rn;
}

// ---------------- K3 (main): fp8 GEMM + ArcFace + per-tile sum-exp2 (fixed shift) ----------------
// BK=64 ([128][64]B tiles), 3 LDS bufs (48KB, 3 blocks/CU), 8 K-steps, 1 s_barrier/step,
// counted vmcnt(4). Reads are ds_read_b128 on 16B slots with XOR swizzle
// slot ^= (r>>1)&3 (round-5-proven 0-conflict geometry); the k-permutation (permj)
// makes each lane's two 8B MFMA frags contiguous. Source pre-swizzled for linear
// global_load_lds dest (rule #21).
__global__ __launch_bounds__(256, 3) void k_gemm8(const unsigned char* __restrict__ ebf8,
                                                  const unsigned char* __restrict__ wbf8,
                                                  float* __restrict__ partials) {
    // XCD-contiguous: XCD x owns wi in [x*1564,(x+1)*1564); 16 rt per ct share B-panel
    const int id = blockIdx.x;
    const int wi = (id & 7) * (NBLK / 8) + (id >> 3);
    const int ct = wi >> 4, rt = wi & 15;
    const int row0 = rt * BM, n0 = ct * BN;
    const int tid = threadIdx.x, lane = tid & 63, wid = tid >> 6;
    const int wm = wid >> 1, wn = wid & 1;

    __shared__ __align__(16) unsigned char lds8[NBUF][16384]; // per buf: A[0,8192) B[8192,16384), [128][64]B each
    float* red = (float*)&lds8[0][0];   // UNION after K-loop: 20480 B < 49152 B

    f32x4 acc[4][4];
    #pragma unroll
    for (int i = 0; i < 4; ++i)
        #pragma unroll
        for (int j = 0; j < 4; ++j)
            acc[i][j] = (f32x4){0.f, 0.f, 0.f, 0.f};

    // ---- staging coords (constant across K-steps) ----
    // Wave w, instr i stages 16B chunks q = w*64 + i*256 + lane (per operand):
    // row r = q>>2 = w*16 + i*64 + (lane>>2), physical slot p = lane&3,
    // logical slot c = p ^ ((r>>1)&3) = (lane&3) ^ ((lane>>3)&3).
    const int c_ = (lane & 3) ^ ((lane >> 3) & 3);
    const int r0s = wid * 16 + (lane >> 2);
    const unsigned char* gA0 = ebf8 + (size_t)(row0 + r0s) * D_ + c_ * 16;
    const unsigned char* gA1 = ebf8 + (size_t)(row0 + 64 + r0s) * D_ + c_ * 16;
    int gb0 = n0 + r0s;      if (gb0 >= V_) gb0 = V_ - 1;   // dup row, masked in epilogue
    int gb1 = n0 + 64 + r0s; if (gb1 >= V_) gb1 = V_ - 1;
    const unsigned char* gB0 = wbf8 + (size_t)gb0 * D_ + c_ * 16;
    const unsigned char* gB1 = wbf8 + (size_t)gb1 * D_ + c_ * 16;
    const int lb = wid * 1024;   // wave-uniform byte offset within each 4096B instr region

    auto STAGE = [&](int t) {
        unsigned char* Lb = &lds8[t % NBUF][0];
        const int off = t * 64;
        load_lds16(gA0 + off, Lb + lb);
        load_lds16(gA1 + off, Lb + 4096 + lb);
        load_lds16(gB0 + off, Lb + 8192 + lb);
        load_lds16(gB1 + off, Lb + 12288 + lb);
    };

    // ---- ds_read_b128 byte offsets (constant): slot = (lane>>4) ^ ((r>>1)&3) ----
    // r = rbase + (lane&15), rbase % 16 == 0 -> (r>>1)&3 == ((lane&15)>>1)&3.
    const int slot = ((lane >> 4) ^ (((lane & 15) >> 1) & 3)) & 3;
    int aoff[4], boff[4];
    #pragma unroll
    for (int mf = 0; mf < 4; ++mf)
        aoff[mf] = (wm * 64 + mf * 16 + (lane & 15)) * 64 + slot * 16;
    #pragma unroll
    for (int nf = 0; nf < 4; ++nf)
        boff[nf] = 8192 + (wn * 64 + nf * 16 + (lane & 15)) * 64 + slot * 16;

    STAGE(0);
    STAGE(1);
    for (int t = 0; t < 8; ++t) {
        // own t-loads (issued at t-2) done; t+1's 4 stay in flight; then block-sync.
        if (t < 7) asm volatile("s_waitcnt vmcnt(4)\n\ts_barrier" ::: "memory");
        else       asm volatile("s_waitcnt vmcnt(0)\n\ts_barrier" ::: "memory");
        if (t + 2 < 8) STAGE(t + 2);   // buf[(t+2)%3] last read at t-1, barrier-ordered safe

        const char* Lb = (const char*)&lds8[t % NBUF][0];
        long2_t a2[4], b2[4];
        #pragma unroll
        for (int mf = 0; mf < 4; ++mf) a2[mf] = *(const long2_t*)(Lb + aoff[mf]);
        #pragma unroll
        for (int nf = 0; nf < 4; ++nf) b2[nf] = *(const long2_t*)(Lb + boff[nf]);
        #pragma unroll
        for (int mf = 0; mf < 4; ++mf)
            #pragma unroll
            for (int nf = 0; nf < 4; ++nf) {
                acc[mf][nf] = __builtin_amdgcn_mfma_f32_16x16x32_fp8_fp8(a2[mf].x, b2[nf].x, acc[mf][nf], 0, 0, 0);
                acc[mf][nf] = __builtin_amdgcn_mfma_f32_16x16x32_fp8_fp8(a2[mf].y, b2[nf].y, acc[mf][nf], 0, 0, 0);
            }
    }
    __syncthreads();   // K-loop LDS reads done before epilogue overwrites the buffers

    // ---- epilogue: ArcFace transform + per-lane exp2 sums (no cross-lane reduce) ----
    const int vlim = V_ - n0;
    #pragma unroll
    for (int mf = 0; mf < 4; ++mf) {
        #pragma unroll
        for (int r = 0; r < 4; ++r) {
            float vsum = 0.0f;
            #pragma unroll
            for (int nf = 0; nf < 4; ++nf) {
                float c = acc[mf][nf][r];
                int coltile = wn * 64 + nf * 16 + (lane & 15);
                c = fminf(fmaxf(c, -1.0f), 1.0f);
                float tt = fmaxf(fmaf(-c, c, 1.0f), 0.0f);
                float st = __builtin_amdgcn_sqrtf(tt);
                float cm = fmaf(c, COS_M_, -st * SIN_M_);
                cm = (c > THRESH) ? cm : (c - MM_);
                float lg = (coltile < vlim) ? cm * S2 : -INFINITY;
                vsum += __builtin_amdgcn_exp2f(lg);   // exp2(-inf) = 0
            }
            int rowloc = wm * 64 + mf * 16 + (lane >> 4) * 4 + r;
            red[(wn * BM + rowloc) * RED_STRIDE + (lane & 15)] = vsum;
        }
    }
    __syncthreads();
    if (tid < BM) {
        const float4* p0 = (const float4*)(red + (size_t)tid * RED_STRIDE);
        const float4* p1 = (const float4*)(red + (size_t)(BM + tid) * RED_STRIDE);
        float s = 0.0f;
        #pragma unroll
        for (int q = 0; q < 4; ++q) {
            float4 u = p0[q], v = p1[q];
            s += (u.x + u.y) + (u.z + u.w) + (v.x + v.y) + (v.z + v.w);
        }
        partials[(size_t)ct * B_ + row0 + tid] = s;   // ct-major: coalesced store
    }
}

// ---------------- fallback GEMM (no workspace): round-5 proven bf16 path ----------------
__device__ __forceinline__ int swz64(int row, int col) {   // [128][64] ushort tile
    return (row * 64 + col) ^ ((row & 7) << 3);
}
__global__ __launch_bounds__(256) void k_gemm_fb(const unsigned short* __restrict__ ebf,
                                                 const float* __restrict__ w,
                                                 const float* __restrict__ rnw,
                                                 float* __restrict__ partials) {
    const int rt = blockIdx.x, ct = blockIdx.y;
    const int row0 = rt * BM, n0 = ct * BN;
    const int tid = threadIdx.x, lane = tid & 63, wid = tid >> 6;
    const int wm = wid >> 1, wn = wid & 1;
    __shared__ __align__(16) unsigned short As[BM * 64];
    __shared__ __align__(16) unsigned short Bs[BN * 64];
    float* red = (float*)&As[0];
    f32x4 acc[4][4];
    #pragma unroll
    for (int i = 0; i < 4; ++i)
        #pragma unroll
        for (int j = 0; j < 4; ++j) acc[i][j] = (f32x4){0.f, 0.f, 0.f, 0.f};
    for (int ks = 0; ks < D_ / 64; ++ks) {
        const int kk = ks * 64;
        #pragma unroll
        for (int p = 0; p < 4; ++p) {
            int idx = p * 256 + tid;
            int r = idx >> 3, c = (idx & 7) * 8;
            *(uint4*)(As + swz64(r, c)) = *(const uint4*)(ebf + (size_t)(row0 + r) * D_ + kk + c);
        }
        #pragma unroll
        for (int p = 0; p < 4; ++p) {
            int idx = p * 256 + tid;
            int r = idx >> 3, c = (idx & 7) * 8;
            int gr = n0 + r;
            uint4 val = make_uint4(0, 0, 0, 0);
            if (gr < V_) {
                float rn = rnw[gr];
                const float4* src = (const float4*)(w + (size_t)gr * D_ + kk + c);
                float4 f0 = src[0], f1 = src[1];
                val.x = (unsigned)f2bf(f0.x*rn) | ((unsigned)f2bf(f0.y*rn) << 16);
                val.y = (unsigned)f2bf(f0.z*rn) | ((unsigned)f2bf(f0.w*rn) << 16);
                val.z = (unsigned)f2bf(f1.x*rn) | ((unsigned)f2bf(f1.y*rn) << 16);
                val.w = (unsigned)f2bf(f1.z*rn) | ((unsigned)f2bf(f1.w*rn) << 16);
            }
            *(uint4*)(Bs + swz64(r, c)) = val;
        }
        __syncthreads();
        #pragma unroll
        for (int kc = 0; kc < 2; ++kc) {
            const int kbase = kc * 32 + (lane >> 4) * 8;
            short8 af[4], bfr[4];
            #pragma unroll
            for (int mf = 0; mf < 4; ++mf) af[mf] = *(const short8*)(As + swz64(wm * 64 + mf * 16 + (lane & 15), kbase));
            #pragma unroll
            for (int nf = 0; nf < 4; ++nf) bfr[nf] = *(const short8*)(Bs + swz64(wn * 64 + nf * 16 + (lane & 15), kbase));
            #pragma unroll
            for (int mf = 0; mf < 4; ++mf)
                #pragma unroll
                for (int nf = 0; nf < 4; ++nf)
                    acc[mf][nf] = __builtin_amdgcn_mfma_f32_16x16x32_bf16(af[mf], bfr[nf], acc[mf][nf], 0, 0, 0);
        }
        __syncthreads();
    }
    const int vlim = V_ - n0;
    #pragma unroll
    for (int mf = 0; mf < 4; ++mf) {
        #pragma unroll
        for (int r = 0; r < 4; ++r) {
            float vsum = 0.0f;
            #pragma unroll
            for (int nf = 0; nf < 4; ++nf) {
                float c = acc[mf][nf][r];
                int coltile = wn * 64 + nf * 16 + (lane & 15);
                c = fminf(fmaxf(c, -1.0f), 1.0f);
                float tt = fmaxf(fmaf(-c, c, 1.0f), 0.0f);
                float st = __builtin_amdgcn_sqrtf(tt);
                float cm = fmaf(c, COS_M_, -st * SIN_M_);
                cm = (c > THRESH) ? cm : (c - MM_);
                float lg = (coltile < vlim) ? cm * S2 : -INFINITY;
                vsum += __builtin_amdgcn_exp2f(lg);
            }
            int rowloc = wm * 64 + mf * 16 + (lane >> 4) * 4 + r;
            red[(wn * BM + rowloc) * RED_STRIDE + (lane & 15)] = vsum;
        }
    }
    __syncthreads();
    if (tid < BM) {
        const float4* p0 = (const float4*)(red + (size_t)tid * RED_STRIDE);
        const float4* p1 = (const float4*)(red + (size_t)(BM + tid) * RED_STRIDE);
        float s = 0.0f;
        #pragma unroll
        for (int q = 0; q < 4; ++q) {
            float4 u = p0[q], v = p1[q];
            s += (u.x + u.y) + (u.z + u.w) + (v.x + v.y) + (v.z + v.w);
        }
        partials[(size_t)ct * B_ + row0 + tid] = s;
    }
}

// label dtype robustness: harness may hand int32 or int64 (LE).
__device__ __forceinline__ int get_label(const int* lab32, int b) {
    bool is64 = true;
    #pragma unroll
    for (int i = 1; i < 16; i += 2) is64 = is64 && (lab32[i] == 0);
    return is64 ? (int)(((const long long*)lab32)[b]) : lab32[b];
}

// ---------------- K4: per-row sum of partials + exact f32 label logit -> nll ----------------
__global__ void k_row(const float* __restrict__ e, const float* __restrict__ w,
                      const int* __restrict__ labels, const float* __restrict__ rne,
                      const float* __restrict__ rnw, const float* __restrict__ partials,
                      float* __restrict__ row_nll) {
    const int b = blockIdx.x;
    const int tid = threadIdx.x;

    float s = 0.0f;
    for (int ctn = tid; ctn < NCT; ctn += 256) s += partials[(size_t)ctn * B_ + b];
    #pragma unroll
    for (int d = 1; d < 64; d <<= 1) s += __shfl_xor(s, d, 64);
    __shared__ float ss_[4], sd_[4];
    if ((tid & 63) == 0) ss_[tid >> 6] = s;

    int lab = get_label(labels, b);
    const float* ep = e + (size_t)b * D_;
    const float* wp = w + (size_t)lab * D_;
    float dot = ep[tid] * wp[tid] + ep[tid + 256] * wp[tid + 256];
    #pragma unroll
    for (int d = 1; d < 64; d <<= 1) dot += __shfl_xor(dot, d, 64);
    if ((tid & 63) == 0) sd_[tid >> 6] = dot;
    __syncthreads();

    if (tid == 0) {
        float S = (ss_[0] + ss_[1]) + (ss_[2] + ss_[3]);
        float lse = __builtin_amdgcn_logf(S) * LN2;   // v_log_f32 = log2; fixed shift M0=0
        float c = (sd_[0] + sd_[1] + sd_[2] + sd_[3]) * rne[b] * rnw[lab];
        c = fminf(fmaxf(c, -1.0f), 1.0f);
        float st = sqrtf(fmaxf(1.0f - c * c, 0.0f));
        float cm = c * COS_M_ - st * SIN_M_;
        cm = (c > THRESH) ? cm : (c - MM_);
        row_nll[b] = lse - cm * S_SCALE;
    }
}

// ---------------- K5: mean ----------------
__global__ void k_mean(const float* __restrict__ row_nll, float* __restrict__ out) {
    int tid = threadIdx.x;
    float s = 0.0f;
    for (int i = tid; i < B_; i += 256) s += row_nll[i];
    #pragma unroll
    for (int d = 1; d < 64; d <<= 1) s += __shfl_xor(s, d, 64);
    __shared__ float sb[4];
    if ((tid & 63) == 0) sb[tid >> 6] = s;
    __syncthreads();
    if (tid == 0) out[0] = (sb[0] + sb[1] + sb[2] + sb[3]) / (float)B_;
}

extern "C" void kernel_launch(void* const* d_in, const int* in_sizes, int n_in,
                              void* d_out, int out_size, void* d_ws, size_t ws_size,
                              hipStream_t stream) {
    const float* e      = (const float*)d_in[0];
    const int*   labels = (const int*)d_in[1];
    const float* w      = (const float*)d_in[2];
    float* out = (float*)d_out;
    char* ws = (char*)d_ws;

    unsigned short* ebf = (unsigned short*)ws;                   // 2,097,152 B
    float* rne          = (float*)(ws + 2097152);                // 8,192 B
    float* rnw          = (float*)(ws + 2105344);                // 400,000 B
    float* partials     = (float*)(ws + 2505344);                // 6,406,144 B (NCT*B_*4)
    float* row_nll      = (float*)(ws + 8911488);                // 8,192 B
    unsigned char* ebf8 = (unsigned char*)(ws + 8919680);        // 1,048,576 B
    unsigned char* wbf8 = (unsigned char*)(ws + 9968256);        // 51,200,000 B
    const size_t NEED_PRE = 9968256 + (size_t)V_ * D_;

    const bool pre = ws_size >= NEED_PRE;

    k_norm_e<<<B_ / 4, 256, 0, stream>>>(e, ebf, pre ? ebf8 : nullptr, rne);
    k_norm_w<<<V_ / 4, 256, 0, stream>>>(w, rnw, pre ? wbf8 : nullptr);
    if (pre) {
        k_gemm8<<<NBLK, 256, 0, stream>>>(ebf8, wbf8, partials);
    } else {
        dim3 g3(B_ / BM, NCT);
        k_gemm_fb<<<g3, 256, 0, stream>>>(ebf, w, rnw, partials);
    }
    k_row<<<B_, 256, 0, stream>>>(e, w, labels, rne, rnw, partials, row_nll);
    k_mean<<<1, 256, 0, stream>>>(row_nll, out);
}

// Round 9
// 208.423 us; speedup vs baseline: 1.9954x; 1.0407x over previous
//
#include <hip/hip_runtime.h>
#include <hip/hip_bf16.h>
#include <math.h>

#define B_ 2048
#define D_ 512
#define V_ 100000
#define BM 128
#define BN 128
#define NCT 782           // ceil(100000/128)
#define NBLK (16 * NCT)   // 12512
#define NBUF 3
#define RED_STRIDE 20     // floats; exact 2-way bank aliasing = free

constexpr float S_SCALE = 64.0f;
constexpr float COS_M_ = 0.8775825618903728f;   // cos(0.5)
constexpr float SIN_M_ = 0.479425538604203f;    // sin(0.5)
constexpr float MM_    = 0.2397127693021015f;   // sin(0.5)*0.5
constexpr float THRESH = -0.8775825618903728f;  // cos(pi-0.5)
constexpr float LOG2E  = 1.4426950408889634f;
constexpr float LN2    = 0.6931471805599453f;
constexpr float S2     = 64.0f * LOG2E;          // logits in base-2 domain
constexpr float CMS2   = COS_M_ * S2;            // 81.0537
constexpr float SINM_S2= SIN_M_ * S2;            // 44.2664
constexpr float KS2    = SINM_S2 * SINM_S2;      // (sinm*S2)^2
constexpr float MMS2   = MM_ * S2;               // 22.1335
// Fixed-shift softmax: lg <= 92.33 (base-2); unshifted sum exp2(lg) stays in
// normal f32 range for any input (max 1e5*2^92.3 = 2^109 < 2^128).

typedef __attribute__((ext_vector_type(8))) short short8;
typedef __attribute__((ext_vector_type(4))) float f32x4;
typedef __attribute__((ext_vector_type(2))) long long2_t;

__device__ __forceinline__ unsigned short f2bf(float x) {
    __hip_bfloat16 h = __float2bfloat16(x);
    unsigned short u;
    __builtin_memcpy(&u, &h, 2);
    return u;
}

__device__ __forceinline__ void load_lds16(const void* g, void* l) {
    __builtin_amdgcn_global_load_lds(
        (const __attribute__((address_space(1))) unsigned int*)g,
        (__attribute__((address_space(3))) unsigned int*)l,
        16, 0, 0);
}

// pack 4 floats -> 4 e4m3 bytes (HW RNE/sat via v_cvt_pk_fp8_f32)
__device__ __forceinline__ unsigned int pk_fp8x4(float x, float y, float z, float w) {
    int p = __builtin_amdgcn_cvt_pk_fp8_f32(x, y, 0, false);
    p = __builtin_amdgcn_cvt_pk_fp8_f32(z, w, p, true);
    return (unsigned int)p;
}

// k-column permutation (4B-block granularity) applied to BOTH fp8 operands:
// within each 64-byte k-group, orig (ks,c,h) [k = 32ks+8c+4h] -> perm block 4c+2ks+h.
// Lane's two 8B MFMA frags (ks=0,1 at chunk c) become ONE contiguous 16B chunk ->
// ds_read_b128 with the proven 16B-slot XOR swizzle (0 bank conflicts, r8-verified).
__device__ __forceinline__ int permj(int j) {   // j = 4B-block index within row
    return (j & ~15) | (((j >> 1) & 3) << 2) | (((j >> 3) & 1) << 1) | (j & 1);
}

// ---------------- K1: normalize embeddings -> bf16 (fallback) + permuted fp8, rnorm_e ----------------
// Block 0 additionally zeroes the 1KB zbuf used for B-padding staging.
__global__ void k_norm_e(const float* __restrict__ e, unsigned short* __restrict__ ebf,
                         unsigned char* __restrict__ ebf8, float* __restrict__ rne,
                         unsigned int* __restrict__ zbuf) {
    if (zbuf && blockIdx.x == 0) zbuf[threadIdx.x] = 0u;   // 256*4B = 1KB zeros
    int row = blockIdx.x * 4 + (threadIdx.x >> 6);
    int lane = threadIdx.x & 63;
    const float4* src = (const float4*)(e + (size_t)row * D_);
    float4 a = src[lane];
    float4 b = src[lane + 64];
    float ss = a.x*a.x + a.y*a.y + a.z*a.z + a.w*a.w
             + b.x*b.x + b.y*b.y + b.z*b.z + b.w*b.w;
    #pragma unroll
    for (int d = 1; d < 64; d <<= 1) ss += __shfl_xor(ss, d, 64);
    float rn = 1.0f / fmaxf(sqrtf(ss), 1e-12f);
    ushort4* dst = (ushort4*)(ebf + (size_t)row * D_);
    dst[lane]      = make_ushort4(f2bf(a.x*rn), f2bf(a.y*rn), f2bf(a.z*rn), f2bf(a.w*rn));
    dst[lane + 64] = make_ushort4(f2bf(b.x*rn), f2bf(b.y*rn), f2bf(b.z*rn), f2bf(b.w*rn));
    if (ebf8) {
        unsigned int* d8 = (unsigned int*)(ebf8 + (size_t)row * D_);
        d8[permj(lane)]      = pk_fp8x4(a.x*rn, a.y*rn, a.z*rn, a.w*rn);
        d8[permj(lane + 64)] = pk_fp8x4(b.x*rn, b.y*rn, b.z*rn, b.w*rn);
    }
    if (lane == 0) rne[row] = rn;
}

// ---------------- K2: weight rnorms + normalized permuted fp8 weight ----------------
__global__ void k_norm_w(const float* __restrict__ w, float* __restrict__ rnw,
                         unsigned char* __restrict__ wbf8) {
    int row = blockIdx.x * 4 + (threadIdx.x >> 6);
    int lane = threadIdx.x & 63;
    const float4* src = (const float4*)(w + (size_t)row * D_);
    float4 a = src[lane];
    float4 b = src[lane + 64];
    float ss = a.x*a.x + a.y*a.y + a.z*a.z + a.w*a.w
             + b.x*b.x + b.y*b.y + b.z*b.z + b.w*b.w;
    #pragma unroll
    for (int d = 1; d < 64; d <<= 1) ss += __shfl_xor(ss, d, 64);
    float rn = 1.0f / fmaxf(sqrtf(ss), 1e-12f);
    if (wbf8) {
        unsigned int* d8 = (unsigned int*)(wbf8 + (size_t)row * D_);
        d8[permj(lane)]      = pk_fp8x4(a.x*rn, a.y*rn, a.z*rn, a.w*rn);
        d8[permj(lane + 64)] = pk_fp8x4(b.x*rn, b.y*rn, b.z*rn, b.w*rn);
    }
    if (lane == 0) rnw[row] = rn;
}

// ---------------- K3 (main): fp8 GEMM + ArcFace + per-tile sum-exp2 (fixed shift) ----------------
// BK=64 ([128][64]B tiles), 3 LDS bufs (48KB, 3 blocks/CU), 8 K-steps, 1 s_barrier/step,
// counted vmcnt(4), ds_read_b128 16B-slot XOR swizzle (0 conflicts, r8-verified).
// r9: trimmed epilogue (8 VALU + 2 trans per logit); OOB B-rows staged as ZEROS
// (zbuf) -> no per-logit validity mask; exact constant correction in k_row.
__global__ __launch_bounds__(256, 3) void k_gemm8(const unsigned char* __restrict__ ebf8,
                                                  const unsigned char* __restrict__ wbf8,
                                                  const unsigned char* __restrict__ zbuf,
                                                  float* __restrict__ partials) {
    // XCD-contiguous: XCD x owns wi in [x*1564,(x+1)*1564); 16 rt per ct share B-panel
    const int id = blockIdx.x;
    const int wi = (id & 7) * (NBLK / 8) + (id >> 3);
    const int ct = wi >> 4, rt = wi & 15;
    const int row0 = rt * BM, n0 = ct * BN;
    const int tid = threadIdx.x, lane = tid & 63, wid = tid >> 6;
    const int wm = wid >> 1, wn = wid & 1;

    __shared__ __align__(16) unsigned char lds8[NBUF][16384]; // per buf: A[0,8192) B[8192,16384), [128][64]B each
    float* red = (float*)&lds8[0][0];   // UNION after K-loop: 20480 B < 49152 B

    f32x4 acc[4][4];
    #pragma unroll
    for (int i = 0; i < 4; ++i)
        #pragma unroll
        for (int j = 0; j < 4; ++j)
            acc[i][j] = (f32x4){0.f, 0.f, 0.f, 0.f};

    // ---- staging coords (constant across K-steps) ----
    const int c_ = (lane & 3) ^ ((lane >> 3) & 3);
    const int r0s = wid * 16 + (lane >> 2);
    const unsigned char* gA0 = ebf8 + (size_t)(row0 + r0s) * D_ + c_ * 16;
    const unsigned char* gA1 = ebf8 + (size_t)(row0 + 64 + r0s) * D_ + c_ * 16;
    int gb0 = n0 + r0s, gb1 = n0 + 64 + r0s;
    // OOB rows stage from the zeroed buffer -> c == 0 logits, corrected in k_row
    const unsigned char* gB0 = (gb0 < V_) ? wbf8 + (size_t)gb0 * D_ + c_ * 16 : zbuf + c_ * 16;
    const unsigned char* gB1 = (gb1 < V_) ? wbf8 + (size_t)gb1 * D_ + c_ * 16 : zbuf + c_ * 16;
    const int lb = wid * 1024;   // wave-uniform byte offset within each 4096B instr region

    auto STAGE = [&](int t) {
        unsigned char* Lb = &lds8[t % NBUF][0];
        const int off = t * 64;
        load_lds16(gA0 + off, Lb + lb);
        load_lds16(gA1 + off, Lb + 4096 + lb);
        load_lds16(gB0 + off, Lb + 8192 + lb);
        load_lds16(gB1 + off, Lb + 12288 + lb);
    };

    // ---- ds_read_b128 byte offsets (constant): slot = (lane>>4) ^ ((r>>1)&3) ----
    const int slot = ((lane >> 4) ^ (((lane & 15) >> 1) & 3)) & 3;
    int aoff[4], boff[4];
    #pragma unroll
    for (int mf = 0; mf < 4; ++mf)
        aoff[mf] = (wm * 64 + mf * 16 + (lane & 15)) * 64 + slot * 16;
    #pragma unroll
    for (int nf = 0; nf < 4; ++nf)
        boff[nf] = 8192 + (wn * 64 + nf * 16 + (lane & 15)) * 64 + slot * 16;

    STAGE(0);
    STAGE(1);
    for (int t = 0; t < 8; ++t) {
        // own t-loads (issued at t-2) done; t+1's 4 stay in flight; then block-sync.
        if (t < 7) asm volatile("s_waitcnt vmcnt(4)\n\ts_barrier" ::: "memory");
        else       asm volatile("s_waitcnt vmcnt(0)\n\ts_barrier" ::: "memory");
        if (t + 2 < 8) STAGE(t + 2);   // buf[(t+2)%3] last read at t-1, barrier-ordered safe

        const char* Lb = (const char*)&lds8[t % NBUF][0];
        long2_t a2[4], b2[4];
        #pragma unroll
        for (int mf = 0; mf < 4; ++mf) a2[mf] = *(const long2_t*)(Lb + aoff[mf]);
        #pragma unroll
        for (int nf = 0; nf < 4; ++nf) b2[nf] = *(const long2_t*)(Lb + boff[nf]);
        #pragma unroll
        for (int mf = 0; mf < 4; ++mf)
            #pragma unroll
            for (int nf = 0; nf < 4; ++nf) {
                acc[mf][nf] = __builtin_amdgcn_mfma_f32_16x16x32_fp8_fp8(a2[mf].x, b2[nf].x, acc[mf][nf], 0, 0, 0);
                acc[mf][nf] = __builtin_amdgcn_mfma_f32_16x16x32_fp8_fp8(a2[mf].y, b2[nf].y, acc[mf][nf], 0, 0, 0);
            }
    }
    __syncthreads();   // K-loop LDS reads done before epilogue overwrites the buffers

    // ---- epilogue: trimmed ArcFace transform, 8 VALU + 2 trans per logit ----
    #pragma unroll
    for (int mf = 0; mf < 4; ++mf) {
        #pragma unroll
        for (int r = 0; r < 4; ++r) {
            float vsum = 0.0f;
            #pragma unroll
            for (int nf = 0; nf < 4; ++nf) {
                float c = acc[mf][nf][r];
                c = __builtin_amdgcn_fmed3f(c, -1.0f, 1.0f);      // clamp
                float tt = fmaf(-c, c, 1.0f);                      // >= 0 after clamp
                float sts = __builtin_amdgcn_sqrtf(tt * KS2);      // sin(th)*sinm*S2
                float lgm = fmaf(c, CMS2, -sts);
                float lga = fmaf(c, S2, -MMS2);
                float lg = (c > THRESH) ? lgm : lga;
                vsum += __builtin_amdgcn_exp2f(lg);
            }
            int rowloc = wm * 64 + mf * 16 + (lane >> 4) * 4 + r;
            red[(wn * BM + rowloc) * RED_STRIDE + (lane & 15)] = vsum;
        }
    }
    __syncthreads();
    if (tid < BM) {
        const float4* p0 = (const float4*)(red + (size_t)tid * RED_STRIDE);
        const float4* p1 = (const float4*)(red + (size_t)(BM + tid) * RED_STRIDE);
        float s = 0.0f;
        #pragma unroll
        for (int q = 0; q < 4; ++q) {
            float4 u = p0[q], v = p1[q];
            s += (u.x + u.y) + (u.z + u.w) + (v.x + v.y) + (v.z + v.w);
        }
        partials[(size_t)ct * B_ + row0 + tid] = s;   // ct-major: coalesced store
    }
}

// ---------------- fallback GEMM (no workspace): round-5 proven bf16 path ----------------
__device__ __forceinline__ int swz64(int row, int col) {   // [128][64] ushort tile
    return (row * 64 + col) ^ ((row & 7) << 3);
}
__global__ __launch_bounds__(256) void k_gemm_fb(const unsigned short* __restrict__ ebf,
                                                 const float* __restrict__ w,
                                                 const float* __restrict__ rnw,
                                                 float* __restrict__ partials) {
    const int rt = blockIdx.x, ct = blockIdx.y;
    const int row0 = rt * BM, n0 = ct * BN;
    const int tid = threadIdx.x, lane = tid & 63, wid = tid >> 6;
    const int wm = wid >> 1, wn = wid & 1;
    __shared__ __align__(16) unsigned short As[BM * 64];
    __shared__ __align__(16) unsigned short Bs[BN * 64];
    float* red = (float*)&As[0];
    f32x4 acc[4][4];
    #pragma unroll
    for (int i = 0; i < 4; ++i)
        #pragma unroll
        for (int j = 0; j < 4; ++j) acc[i][j] = (f32x4){0.f, 0.f, 0.f, 0.f};
    for (int ks = 0; ks < D_ / 64; ++ks) {
        const int kk = ks * 64;
        #pragma unroll
        for (int p = 0; p < 4; ++p) {
            int idx = p * 256 + tid;
            int r = idx >> 3, c = (idx & 7) * 8;
            *(uint4*)(As + swz64(r, c)) = *(const uint4*)(ebf + (size_t)(row0 + r) * D_ + kk + c);
        }
        #pragma unroll
        for (int p = 0; p < 4; ++p) {
            int idx = p * 256 + tid;
            int r = idx >> 3, c = (idx & 7) * 8;
            int gr = n0 + r;
            uint4 val = make_uint4(0, 0, 0, 0);
            if (gr < V_) {
                float rn = rnw[gr];
                const float4* src = (const float4*)(w + (size_t)gr * D_ + kk + c);
                float4 f0 = src[0], f1 = src[1];
                val.x = (unsigned)f2bf(f0.x*rn) | ((unsigned)f2bf(f0.y*rn) << 16);
                val.y = (unsigned)f2bf(f0.z*rn) | ((unsigned)f2bf(f0.w*rn) << 16);
                val.z = (unsigned)f2bf(f1.x*rn) | ((unsigned)f2bf(f1.y*rn) << 16);
                val.w = (unsigned)f2bf(f1.z*rn) | ((unsigned)f2bf(f1.w*rn) << 16);
            }
            *(uint4*)(Bs + swz64(r, c)) = val;
        }
        __syncthreads();
        #pragma unroll
        for (int kc = 0; kc < 2; ++kc) {
            const int kbase = kc * 32 + (lane >> 4) * 8;
            short8 af[4], bfr[4];
            #pragma unroll
            for (int mf = 0; mf < 4; ++mf) af[mf] = *(const short8*)(As + swz64(wm * 64 + mf * 16 + (lane & 15), kbase));
            #pragma unroll
            for (int nf = 0; nf < 4; ++nf) bfr[nf] = *(const short8*)(Bs + swz64(wn * 64 + nf * 16 + (lane & 15), kbase));
            #pragma unroll
            for (int mf = 0; mf < 4; ++mf)
                #pragma unroll
                for (int nf = 0; nf < 4; ++nf)
                    acc[mf][nf] = __builtin_amdgcn_mfma_f32_16x16x32_bf16(af[mf], bfr[nf], acc[mf][nf], 0, 0, 0);
        }
        __syncthreads();
    }
    const int vlim = V_ - n0;
    #pragma unroll
    for (int mf = 0; mf < 4; ++mf) {
        #pragma unroll
        for (int r = 0; r < 4; ++r) {
            float vsum = 0.0f;
            #pragma unroll
            for (int nf = 0; nf < 4; ++nf) {
                float c = acc[mf][nf][r];
                int coltile = wn * 64 + nf * 16 + (lane & 15);
                c = __builtin_amdgcn_fmed3f(c, -1.0f, 1.0f);
                float tt = fmaf(-c, c, 1.0f);
                float sts = __builtin_amdgcn_sqrtf(tt * KS2);
                float lgm = fmaf(c, CMS2, -sts);
                float lga = fmaf(c, S2, -MMS2);
                float lg = (c > THRESH) ? lgm : lga;
                lg = (coltile < vlim) ? lg : -INFINITY;
                vsum += __builtin_amdgcn_exp2f(lg);
            }
            int rowloc = wm * 64 + mf * 16 + (lane >> 4) * 4 + r;
            red[(wn * BM + rowloc) * RED_STRIDE + (lane & 15)] = vsum;
        }
    }
    __syncthreads();
    if (tid < BM) {
        const float4* p0 = (const float4*)(red + (size_t)tid * RED_STRIDE);
        const float4* p1 = (const float4*)(red + (size_t)(BM + tid) * RED_STRIDE);
        float s = 0.0f;
        #pragma unroll
        for (int q = 0; q < 4; ++q) {
            float4 u = p0[q], v = p1[q];
            s += (u.x + u.y) + (u.z + u.w) + (v.x + v.y) + (v.z + v.w);
        }
        partials[(size_t)ct * B_ + row0 + tid] = s;
    }
}

// label dtype robustness: harness may hand int32 or int64 (LE).
__device__ __forceinline__ int get_label(const int* lab32, int b) {
    bool is64 = true;
    #pragma unroll
    for (int i = 1; i < 16; i += 2) is64 = is64 && (lab32[i] == 0);
    return is64 ? (int)(((const long long*)lab32)[b]) : lab32[b];
}

// ---------------- K4: per-row sum of partials (minus pad correction) + exact label logit ----------------
__global__ void k_row(const float* __restrict__ e, const float* __restrict__ w,
                      const int* __restrict__ labels, const float* __restrict__ rne,
                      const float* __restrict__ rnw, const float* __restrict__ partials,
                      float* __restrict__ row_nll, float padcorr) {
    const int b = blockIdx.x;
    const int tid = threadIdx.x;

    float s = 0.0f;
    for (int ctn = tid; ctn < NCT; ctn += 256) s += partials[(size_t)ctn * B_ + b];
    #pragma unroll
    for (int d = 1; d < 64; d <<= 1) s += __shfl_xor(s, d, 64);
    __shared__ float ss_[4], sd_[4];
    if ((tid & 63) == 0) ss_[tid >> 6] = s;

    int lab = get_label(labels, b);
    const float* ep = e + (size_t)b * D_;
    const float* wp = w + (size_t)lab * D_;
    float dot = ep[tid] * wp[tid] + ep[tid + 256] * wp[tid + 256];
    #pragma unroll
    for (int d = 1; d < 64; d <<= 1) dot += __shfl_xor(dot, d, 64);
    if ((tid & 63) == 0) sd_[tid >> 6] = dot;
    __syncthreads();

    if (tid == 0) {
        float S = (ss_[0] + ss_[1]) + (ss_[2] + ss_[3]) - padcorr;  // remove zero-pad cols
        float lse = __builtin_amdgcn_logf(S) * LN2;   // v_log_f32 = log2; fixed shift M0=0
        float c = (sd_[0] + sd_[1] + sd_[2] + sd_[3]) * rne[b] * rnw[lab];
        c = fminf(fmaxf(c, -1.0f), 1.0f);
        float st = sqrtf(fmaxf(1.0f - c * c, 0.0f));
        float cm = c * COS_M_ - st * SIN_M_;
        cm = (c > THRESH) ? cm : (c - MM_);
        row_nll[b] = lse - cm * S_SCALE;
    }
}

// ---------------- K5: mean ----------------
__global__ void k_mean(const float* __restrict__ row_nll, float* __restrict__ out) {
    int tid = threadIdx.x;
    float s = 0.0f;
    for (int i = tid; i < B_; i += 256) s += row_nll[i];
    #pragma unroll
    for (int d = 1; d < 64; d <<= 1) s += __shfl_xor(s, d, 64);
    __shared__ float sb[4];
    if ((tid & 63) == 0) sb[tid >> 6] = s;
    __syncthreads();
    if (tid == 0) out[0] = (sb[0] + sb[1] + sb[2] + sb[3]) / (float)B_;
}

extern "C" void kernel_launch(void* const* d_in, const int* in_sizes, int n_in,
                              void* d_out, int out_size, void* d_ws, size_t ws_size,
                              hipStream_t stream) {
    const float* e      = (const float*)d_in[0];
    const int*   labels = (const int*)d_in[1];
    const float* w      = (const float*)d_in[2];
    float* out = (float*)d_out;
    char* ws = (char*)d_ws;

    unsigned short* ebf = (unsigned short*)ws;                   // 2,097,152 B
    float* rne          = (float*)(ws + 2097152);                // 8,192 B
    float* rnw          = (float*)(ws + 2105344);                // 400,000 B
    float* partials     = (float*)(ws + 2505344);                // 6,406,144 B (NCT*B_*4)
    float* row_nll      = (float*)(ws + 8911488);                // 8,192 B
    unsigned int* zbuf  = (unsigned int*)(ws + 8919680);         // 4,096 B zero staging
    unsigned char* ebf8 = (unsigned char*)(ws + 8923776);        // 1,048,576 B
    unsigned char* wbf8 = (unsigned char*)(ws + 9972352);        // 51,200,000 B
    const size_t NEED_PRE = 9972352 + (size_t)V_ * D_;

    const bool pre = ws_size >= NEED_PRE;
    // exact correction: 96 padding cols, each contributing exp2(-sinm*S2) (c = 0)
    const float padcorr = pre ? 96.0f * exp2f(-(float)SINM_S2) : 0.0f;

    k_norm_e<<<B_ / 4, 256, 0, stream>>>(e, ebf, pre ? ebf8 : nullptr, rne, pre ? zbuf : nullptr);
    k_norm_w<<<V_ / 4, 256, 0, stream>>>(w, rnw, pre ? wbf8 : nullptr);
    if (pre) {
        k_gemm8<<<NBLK, 256, 0, stream>>>(ebf8, wbf8, (const unsigned char*)zbuf, partials);
    } else {
        dim3 g3(B_ / BM, NCT);
        k_gemm_fb<<<g3, 256, 0, stream>>>(ebf, w, rnw, partials);
    }
    k_row<<<B_, 256, 0, stream>>>(e, w, labels, rne, rnw, partials, row_nll, padcorr);
    k_mean<<<1, 256, 0, stream>>>(row_nll, out);
}